// Round 1
// baseline (963.780 us; speedup 1.0000x reference)
//
#include <hip/hip_runtime.h>
#include <cmath>

#define BB 64
#define NN 883
#define EE 10
#define CC 66

__device__ __forceinline__ float sigmoidf_(float v) { return 1.f / (1.f + expf(-v)); }

// ---------------- K1: concat + hyper-MLP + nodevec (stored transposed) ----------------
template<int PHASE>
__global__ __launch_bounds__(256) void k1_hyper(
    const float* __restrict__ x, const float* __restrict__ state,
    const float* __restrict__ zr, const float* __restrict__ emb,
    const float* __restrict__ tme, const float* __restrict__ day,
    const float* __restrict__ spd, const float* __restrict__ occ,
    const float* __restrict__ w1, const float* __restrict__ b1,
    const float* __restrict__ w2, const float* __restrict__ b2,
    const float* __restrict__ w3, const float* __restrict__ b3,
    float* __restrict__ xs_g, float* __restrict__ nvT_g) {
  int bn = blockIdx.x * 256 + threadIdx.x;
  if (bn >= BB * NN) return;
  int b = bn / NN, n = bn - b * NN;

  float xsr[CC];
  xsr[0] = x[bn * 2 + 0];
  xsr[1] = x[bn * 2 + 1];
#pragma unroll
  for (int j = 0; j < 64; ++j) {
    float s = state[bn * 64 + j];
    if (PHASE == 1) s *= zr[bn * 128 + j];   // z = first half of sigmoid(z_r)
    xsr[2 + j] = s;
  }
#pragma unroll
  for (int c = 0; c < CC; ++c) xs_g[bn * CC + c] = xsr[c];

  float h1[16];
#pragma unroll
  for (int j = 0; j < 16; ++j) h1[j] = b1[j];
#pragma unroll
  for (int i = 0; i < CC; ++i) {
    float xv = xsr[i];
#pragma unroll
    for (int j = 0; j < 16; ++j) h1[j] = fmaf(xv, w1[i * 16 + j], h1[j]);
  }
#pragma unroll
  for (int j = 0; j < 16; ++j) h1[j] = sigmoidf_(h1[j]);

  float h2[2];
#pragma unroll
  for (int j = 0; j < 2; ++j) {
    float s = b2[j];
#pragma unroll
    for (int i = 0; i < 16; ++i) s = fmaf(h1[i], w2[i * 2 + j], s);
    h2[j] = sigmoidf_(s);
  }

#pragma unroll
  for (int e = 0; e < EE; ++e) {
    float f = b3[e] + h2[0] * w3[e] + h2[1] * w3[EE + e];
    int be = bn * EE + e;
    float dyn = emb[n * EE + e] * tme[be] * day[be] * spd[be] * occ[be];
    nvT_g[(b * EE + e) * NN + n] = tanhf(dyn * f);  // transposed: [b][e][n]
  }
}

// ---------------- K2: degree d = rsqrt(rowsum(relu(nv nv^T))) ----------------
__global__ __launch_bounds__(256) void k2_deg(const float* __restrict__ nvT_g,
                                              float* __restrict__ dd_g) {
  int nt = blockIdx.x, b = blockIdx.y;
  int t = threadIdx.x;
  __shared__ __align__(16) float nvn[EE * 132];   // [e][nl<128]
  __shared__ __align__(16) float nvm[EE * 68];    // [e][ml<64]
  __shared__ __align__(16) float rs_s[16 * 132];
  int nb = nt * 128;

  for (int idx = t; idx < EE * 128; idx += 256) {
    int e = idx >> 7, nl = idx & 127;
    int n = nb + nl;
    nvn[e * 132 + nl] = (n < NN) ? nvT_g[(b * EE + e) * NN + n] : 0.f;
  }

  int tn = t & 15, tm = t >> 4;  // 16 n-groups (8n) x 16 m-groups (4m)
  float rs[8] = {0.f, 0.f, 0.f, 0.f, 0.f, 0.f, 0.f, 0.f};

  for (int s5 = 0; s5 < 14; ++s5) {
    int mb = s5 * 64;
    __syncthreads();
    for (int idx = t; idx < EE * 64; idx += 256) {
      int e = idx >> 6, ml = idx & 63;
      int m = mb + ml;
      nvm[e * 68 + ml] = (m < NN) ? nvT_g[(b * EE + e) * NN + m] : 0.f;
    }
    __syncthreads();

    float G[8][4];
#pragma unroll
    for (int i = 0; i < 8; ++i)
#pragma unroll
      for (int j = 0; j < 4; ++j) G[i][j] = 0.f;
#pragma unroll
    for (int e = 0; e < EE; ++e) {
      float4 a0 = *(const float4*)&nvn[e * 132 + tn * 8];
      float4 a1 = *(const float4*)&nvn[e * 132 + tn * 8 + 4];
      float4 bm = *(const float4*)&nvm[e * 68 + tm * 4];
      float av[8] = {a0.x, a0.y, a0.z, a0.w, a1.x, a1.y, a1.z, a1.w};
      float bv[4] = {bm.x, bm.y, bm.z, bm.w};
#pragma unroll
      for (int i = 0; i < 8; ++i)
#pragma unroll
        for (int j = 0; j < 4; ++j) G[i][j] = fmaf(av[i], bv[j], G[i][j]);
    }
#pragma unroll
    for (int i = 0; i < 8; ++i)
#pragma unroll
      for (int j = 0; j < 4; ++j) rs[i] += fmaxf(G[i][j], 0.f);
  }

  *(float4*)&rs_s[tm * 132 + tn * 8] = make_float4(rs[0], rs[1], rs[2], rs[3]);
  *(float4*)&rs_s[tm * 132 + tn * 8 + 4] = make_float4(rs[4], rs[5], rs[6], rs[7]);
  __syncthreads();
  if (t < 128) {
    float s = 0.f;
#pragma unroll
    for (int q = 0; q < 16; ++q) s += rs_s[q * 132 + t];
    int n = nb + t;
    if (n < NN) dd_g[b * NN + n] = 1.f / sqrtf(s);
  }
}

// ---------------- K3: y[b,n,c] = d[n] * sum_m relu(nv.nv) d[m] xs[m,c] ----------------
__global__ __launch_bounds__(256) void k3_agg(const float* __restrict__ nvT_g,
                                              const float* __restrict__ dd_g,
                                              const float* __restrict__ xs_g,
                                              float* __restrict__ yr_g) {
  int nt = blockIdx.x, b = blockIdx.y;
  int t = threadIdx.x;
  __shared__ __align__(16) float nvn[EE * 132];   // [e][nl<128]
  __shared__ __align__(16) float nvm[EE * 36];    // [e][ml<32]
  __shared__ __align__(16) float AsT[32 * 132];   // [ml][nl]  A*d[m]
  __shared__ __align__(16) float xs_s[32 * 72];   // [ml][c<72]
  __shared__ float dd_n[128];
  __shared__ float dd_m[32];
  int nb = nt * 128;

  for (int idx = t; idx < EE * 128; idx += 256) {
    int e = idx >> 7, nl = idx & 127;
    int n = nb + nl;
    nvn[e * 132 + nl] = (n < NN) ? nvT_g[(b * EE + e) * NN + n] : 0.f;
  }
  if (t < 128) {
    int n = nb + t;
    dd_n[t] = (n < NN) ? dd_g[b * NN + n] : 0.f;
  }

  int tn = t & 15, tg = t >> 4;  // stage1: t<128 (tg<8); stage2: t<144 (tg<=8)
  float acc[8][8];
#pragma unroll
  for (int i = 0; i < 8; ++i)
#pragma unroll
    for (int j = 0; j < 8; ++j) acc[i][j] = 0.f;

  for (int s5 = 0; s5 < 28; ++s5) {
    int mb = s5 * 32;
    __syncthreads();  // protect prev iteration's reads
    for (int idx = t; idx < EE * 32; idx += 256) {
      int e = idx >> 5, ml = idx & 31;
      int m = mb + ml;
      nvm[e * 36 + ml] = (m < NN) ? nvT_g[(b * EE + e) * NN + m] : 0.f;
    }
    if (t < 32) {
      int m = mb + t;
      dd_m[t] = (m < NN) ? dd_g[b * NN + m] : 0.f;
    }
    for (int idx = t; idx < 32 * CC; idx += 256) {
      int ml = idx / CC, c = idx - ml * CC;
      int m = mb + ml;
      xs_s[ml * 72 + c] = (m < NN) ? xs_g[(b * NN + m) * CC + c] : 0.f;
    }
    for (int idx = t; idx < 32 * 6; idx += 256) {
      int ml = idx / 6, c = CC + (idx - ml * 6);
      xs_s[ml * 72 + c] = 0.f;
    }
    __syncthreads();

    // stage 1: A tile (128n x 32m), 8n x 4m per thread, t<128
    if (t < 128) {
      float G[8][4];
#pragma unroll
      for (int i = 0; i < 8; ++i)
#pragma unroll
        for (int j = 0; j < 4; ++j) G[i][j] = 0.f;
#pragma unroll
      for (int e = 0; e < EE; ++e) {
        float4 a0 = *(const float4*)&nvn[e * 132 + tn * 8];
        float4 a1 = *(const float4*)&nvn[e * 132 + tn * 8 + 4];
        float4 bm = *(const float4*)&nvm[e * 36 + tg * 4];
        float av[8] = {a0.x, a0.y, a0.z, a0.w, a1.x, a1.y, a1.z, a1.w};
        float bv[4] = {bm.x, bm.y, bm.z, bm.w};
#pragma unroll
        for (int i = 0; i < 8; ++i)
#pragma unroll
          for (int j = 0; j < 4; ++j) G[i][j] = fmaf(av[i], bv[j], G[i][j]);
      }
#pragma unroll
      for (int j = 0; j < 4; ++j) {
        int ml = tg * 4 + j;
        float dm = dd_m[ml];
        float4 v0 = make_float4(fmaxf(G[0][j], 0.f) * dm, fmaxf(G[1][j], 0.f) * dm,
                                fmaxf(G[2][j], 0.f) * dm, fmaxf(G[3][j], 0.f) * dm);
        float4 v1 = make_float4(fmaxf(G[4][j], 0.f) * dm, fmaxf(G[5][j], 0.f) * dm,
                                fmaxf(G[6][j], 0.f) * dm, fmaxf(G[7][j], 0.f) * dm);
        *(float4*)&AsT[ml * 132 + tn * 8] = v0;
        *(float4*)&AsT[ml * 132 + tn * 8 + 4] = v1;
      }
    }
    __syncthreads();

    // stage 2: acc[8n][8c] += A[n][m] * xs[m][c], t<144
    if (t < 144) {
      for (int ml = 0; ml < 32; ++ml) {
        float4 A0 = *(const float4*)&AsT[ml * 132 + tn * 8];
        float4 A1 = *(const float4*)&AsT[ml * 132 + tn * 8 + 4];
        float4 X0 = *(const float4*)&xs_s[ml * 72 + tg * 8];
        float4 X1 = *(const float4*)&xs_s[ml * 72 + tg * 8 + 4];
        float av[8] = {A0.x, A0.y, A0.z, A0.w, A1.x, A1.y, A1.z, A1.w};
        float xv[8] = {X0.x, X0.y, X0.z, X0.w, X1.x, X1.y, X1.z, X1.w};
#pragma unroll
        for (int i = 0; i < 8; ++i)
#pragma unroll
          for (int j = 0; j < 8; ++j) acc[i][j] = fmaf(av[i], xv[j], acc[i][j]);
      }
    }
  }

  if (t < 144) {
#pragma unroll
    for (int i = 0; i < 8; ++i) {
      int n = nb + tn * 8 + i;
      if (n < NN) {
        float dn = dd_n[tn * 8 + i];
#pragma unroll
        for (int j = 0; j < 8; ++j) {
          int c = tg * 8 + j;
          if (c < CC) yr_g[(b * NN + n) * CC + c] = dn * acc[i][j];
        }
      }
    }
  }
}

// ---------------- K4: per-node weight contraction + GRU epilogue ----------------
// out_pre[o] = bias + sum_i xs_i*(W0+W1)[i][o] - y_i*W1[i][o]   (fold of L = I - Anorm)
template<int OTOT, bool GATE>
__global__ __launch_bounds__(256) void k4_out(
    const float* __restrict__ emb, const float* __restrict__ wpool,
    const float* __restrict__ bpool, const float* __restrict__ xs_g,
    const float* __restrict__ yr_g, float* __restrict__ zr_w,
    const float* __restrict__ state, const float* __restrict__ zr_r,
    float* __restrict__ out) {
  int n = blockIdx.x, t = threadIdx.x;
  int o_off = blockIdx.y * 64;
  __shared__ __align__(16) float W0s[CC * 64];
  __shared__ __align__(16) float W1s[CC * 64];
  __shared__ __align__(16) float xsT[CC * 36];
  __shared__ __align__(16) float yrT[CC * 36];
  __shared__ float bias_s[64];
  __shared__ float emb_s[EE];

  if (t < EE) emb_s[t] = emb[n * EE + t];
  __syncthreads();

  for (int idx = t; idx < CC * 64; idx += 256) {
    int i = idx >> 6, o = idx & 63;
    float s0 = 0.f, s1 = 0.f;
#pragma unroll
    for (int e = 0; e < EE; ++e) {
      float em = emb_s[e];
      s0 = fmaf(em, wpool[((e * 2 + 0) * CC + i) * OTOT + o_off + o], s0);
      s1 = fmaf(em, wpool[((e * 2 + 1) * CC + i) * OTOT + o_off + o], s1);
    }
    W0s[idx] = s0 + s1;  // W0 + W1
    W1s[idx] = s1;
  }
  if (t < 64) {
    float s = 0.f;
#pragma unroll
    for (int e = 0; e < EE; ++e) s = fmaf(emb_s[e], bpool[e * OTOT + o_off + t], s);
    bias_s[t] = s;
  }

  for (int bp = 0; bp < 2; ++bp) {
    __syncthreads();
    for (int idx = t; idx < 32 * CC; idx += 256) {
      int bl = idx / CC, i = idx - bl * CC;
      int bb = bp * 32 + bl;
      xsT[i * 36 + bl] = xs_g[(bb * NN + n) * CC + i];
      yrT[i * 36 + bl] = yr_g[(bb * NN + n) * CC + i];
    }
    __syncthreads();

    if (t < 64) {
      int og = t & 7, bg = t >> 3;
      int o0 = og * 8, bl0 = bg * 4;
      float acc[8][4];
#pragma unroll
      for (int oi = 0; oi < 8; ++oi)
#pragma unroll
        for (int bj = 0; bj < 4; ++bj) acc[oi][bj] = bias_s[o0 + oi];
      for (int i = 0; i < CC; ++i) {
        float4 w0a = *(const float4*)&W0s[i * 64 + o0];
        float4 w0b = *(const float4*)&W0s[i * 64 + o0 + 4];
        float4 w1a = *(const float4*)&W1s[i * 64 + o0];
        float4 w1b = *(const float4*)&W1s[i * 64 + o0 + 4];
        float4 xv4 = *(const float4*)&xsT[i * 36 + bl0];
        float4 yv4 = *(const float4*)&yrT[i * 36 + bl0];
        float w0[8] = {w0a.x, w0a.y, w0a.z, w0a.w, w0b.x, w0b.y, w0b.z, w0b.w};
        float w1[8] = {w1a.x, w1a.y, w1a.z, w1a.w, w1b.x, w1b.y, w1b.z, w1b.w};
        float xv[4] = {xv4.x, xv4.y, xv4.z, xv4.w};
        float nyv[4] = {-yv4.x, -yv4.y, -yv4.z, -yv4.w};
#pragma unroll
        for (int oi = 0; oi < 8; ++oi)
#pragma unroll
          for (int bj = 0; bj < 4; ++bj) {
            acc[oi][bj] = fmaf(w0[oi], xv[bj], acc[oi][bj]);
            acc[oi][bj] = fmaf(w1[oi], nyv[bj], acc[oi][bj]);
          }
      }
#pragma unroll
      for (int oi = 0; oi < 8; ++oi) {
        int o = o_off + o0 + oi;
#pragma unroll
        for (int bj = 0; bj < 4; ++bj) {
          int bb = bp * 32 + bl0 + bj;
          float v = acc[oi][bj];
          if (GATE) {
            zr_w[(bb * NN + n) * 128 + o] = sigmoidf_(v);
          } else {
            float hc = tanhf(v);
            float r = zr_r[(bb * NN + n) * 128 + 64 + o];
            float st = state[(bb * NN + n) * 64 + o];
            out[(bb * NN + n) * 64 + o] = fmaf(r, st - hc, hc);  // r*st + (1-r)*hc
          }
        }
      }
    }
  }
}

extern "C" void kernel_launch(void* const* d_in, const int* in_sizes, int n_in,
                              void* d_out, int out_size, void* d_ws, size_t ws_size,
                              hipStream_t stream) {
  const float* x     = (const float*)d_in[0];
  const float* state = (const float*)d_in[1];
  const float* emb   = (const float*)d_in[2];
  const float* tme   = (const float*)d_in[3];
  const float* day   = (const float*)d_in[4];
  const float* spd   = (const float*)d_in[5];
  const float* occ   = (const float*)d_in[6];
  const float* gwp   = (const float*)d_in[7];
  const float* gbp   = (const float*)d_in[8];
  const float* gw1   = (const float*)d_in[9];
  const float* gb1   = (const float*)d_in[10];
  const float* gw2   = (const float*)d_in[11];
  const float* gb2   = (const float*)d_in[12];
  const float* gw3   = (const float*)d_in[13];
  const float* gb3   = (const float*)d_in[14];
  const float* uwp   = (const float*)d_in[15];
  const float* ubp   = (const float*)d_in[16];
  const float* uw1   = (const float*)d_in[17];
  const float* ub1   = (const float*)d_in[18];
  const float* uw2   = (const float*)d_in[19];
  const float* ub2   = (const float*)d_in[20];
  const float* uw3   = (const float*)d_in[21];
  const float* ub3   = (const float*)d_in[22];

  float* ws  = (float*)d_ws;
  float* xs  = ws;                             // B*N*66  = 3,729,792
  float* nvT = xs + (size_t)BB * NN * CC;      // B*10*N  =   565,120
  float* dd  = nvT + (size_t)BB * EE * NN;     // B*N     =    56,512
  float* yr  = dd + (size_t)BB * NN;           // B*N*66  = 3,729,792
  float* zr  = yr + (size_t)BB * NN * CC;      // B*N*128 = 7,233,536
  // total 15,314,752 floats = 61.3 MB

  dim3 blk(256);
  dim3 gK1((BB * NN + 255) / 256);
  dim3 gK2(7, BB);
  dim3 gK4g(NN, 2), gK4u(NN, 1);

  // phase A (gate)
  k1_hyper<0><<<gK1, blk, 0, stream>>>(x, state, zr, emb, tme, day, spd, occ,
                                       gw1, gb1, gw2, gb2, gw3, gb3, xs, nvT);
  k2_deg<<<gK2, blk, 0, stream>>>(nvT, dd);
  k3_agg<<<gK2, blk, 0, stream>>>(nvT, dd, xs, yr);
  k4_out<128, true><<<gK4g, blk, 0, stream>>>(emb, gwp, gbp, xs, yr, zr,
                                              nullptr, nullptr, nullptr);
  // phase B (update)
  k1_hyper<1><<<gK1, blk, 0, stream>>>(x, state, zr, emb, tme, day, spd, occ,
                                       uw1, ub1, uw2, ub2, uw3, ub3, xs, nvT);
  k2_deg<<<gK2, blk, 0, stream>>>(nvT, dd);
  k3_agg<<<gK2, blk, 0, stream>>>(nvT, dd, xs, yr);
  k4_out<64, false><<<gK4u, blk, 0, stream>>>(emb, uwp, ubp, xs, yr, nullptr,
                                              state, zr, (float*)d_out);
}

// Round 2
// 820.082 us; speedup vs baseline: 1.1752x; 1.1752x over previous
//
#include <hip/hip_runtime.h>
#include <cmath>

#define BB 64
#define NN 883
#define EE 10
#define CC 66

__device__ __forceinline__ float sigmoidf_(float v) { return 1.f / (1.f + expf(-v)); }

// ---------------- K1: concat + hyper-MLP + nodevec (stored transposed) ----------------
template<int PHASE>
__global__ __launch_bounds__(256) void k1_hyper(
    const float* __restrict__ x, const float* __restrict__ state,
    const float* __restrict__ zr, const float* __restrict__ emb,
    const float* __restrict__ tme, const float* __restrict__ day,
    const float* __restrict__ spd, const float* __restrict__ occ,
    const float* __restrict__ w1, const float* __restrict__ b1,
    const float* __restrict__ w2, const float* __restrict__ b2,
    const float* __restrict__ w3, const float* __restrict__ b3,
    float* __restrict__ xs_g, float* __restrict__ nvT_g) {
  int bn = blockIdx.x * 256 + threadIdx.x;
  if (bn >= BB * NN) return;
  int b = bn / NN, n = bn - b * NN;

  float xsr[CC];
  xsr[0] = x[bn * 2 + 0];
  xsr[1] = x[bn * 2 + 1];
#pragma unroll
  for (int j = 0; j < 64; ++j) {
    float s = state[bn * 64 + j];
    if (PHASE == 1) s *= zr[bn * 128 + j];   // z = first half of sigmoid(z_r)
    xsr[2 + j] = s;
  }
#pragma unroll
  for (int c = 0; c < CC; ++c) xs_g[bn * CC + c] = xsr[c];

  float h1[16];
#pragma unroll
  for (int j = 0; j < 16; ++j) h1[j] = b1[j];
#pragma unroll
  for (int i = 0; i < CC; ++i) {
    float xv = xsr[i];
#pragma unroll
    for (int j = 0; j < 16; ++j) h1[j] = fmaf(xv, w1[i * 16 + j], h1[j]);
  }
#pragma unroll
  for (int j = 0; j < 16; ++j) h1[j] = sigmoidf_(h1[j]);

  float h2[2];
#pragma unroll
  for (int j = 0; j < 2; ++j) {
    float s = b2[j];
#pragma unroll
    for (int i = 0; i < 16; ++i) s = fmaf(h1[i], w2[i * 2 + j], s);
    h2[j] = sigmoidf_(s);
  }

#pragma unroll
  for (int e = 0; e < EE; ++e) {
    float f = b3[e] + h2[0] * w3[e] + h2[1] * w3[EE + e];
    int be = bn * EE + e;
    float dyn = emb[n * EE + e] * tme[be] * day[be] * spd[be] * occ[be];
    nvT_g[(b * EE + e) * NN + n] = tanhf(dyn * f);  // transposed: [b][e][n]
  }
}

// ---------------- K2: partial rowsum of relu(nv nv^T) over an m-half ----------------
// grid (7, BB, 2); 128 threads; 8n x 8m per thread (ratio 1.0 FMA/lane-byte)
__global__ __launch_bounds__(128) void k2_deg(const float* __restrict__ nvT_g,
                                              float* __restrict__ dd0,
                                              float* __restrict__ dd1) {
  int nt = blockIdx.x, b = blockIdx.y, z = blockIdx.z;
  int t = threadIdx.x;
  __shared__ __align__(16) float nvn[EE * 132];   // [e][nl<128]
  __shared__ __align__(16) float nvm[EE * 68];    // [e][ml<64]
  __shared__ __align__(16) float rs_s[8 * 132];
  int nb = nt * 128;

  for (int idx = t; idx < EE * 128; idx += 128) {
    int e = idx >> 7, nl = idx & 127;
    int n = nb + nl;
    nvn[e * 132 + nl] = (n < NN) ? nvT_g[(b * EE + e) * NN + n] : 0.f;
  }

  int tn = t & 15, tm = t >> 4;  // 16 n-groups(8n) x 8 m-groups(8m)
  float rs[8] = {0.f, 0.f, 0.f, 0.f, 0.f, 0.f, 0.f, 0.f};

  for (int s5 = 0; s5 < 7; ++s5) {
    int mb = (z * 7 + s5) * 64;
    __syncthreads();
    for (int idx = t; idx < EE * 64; idx += 128) {
      int e = idx >> 6, ml = idx & 63;
      int m = mb + ml;
      nvm[e * 68 + ml] = (m < NN) ? nvT_g[(b * EE + e) * NN + m] : 0.f;
    }
    __syncthreads();

    float G[8][8];
#pragma unroll
    for (int i = 0; i < 8; ++i)
#pragma unroll
      for (int j = 0; j < 8; ++j) G[i][j] = 0.f;
#pragma unroll
    for (int e = 0; e < EE; ++e) {
      float4 a0 = *(const float4*)&nvn[e * 132 + tn * 8];
      float4 a1 = *(const float4*)&nvn[e * 132 + tn * 8 + 4];
      float4 b0 = *(const float4*)&nvm[e * 68 + tm * 8];
      float4 b1v = *(const float4*)&nvm[e * 68 + tm * 8 + 4];
      float av[8] = {a0.x, a0.y, a0.z, a0.w, a1.x, a1.y, a1.z, a1.w};
      float bv[8] = {b0.x, b0.y, b0.z, b0.w, b1v.x, b1v.y, b1v.z, b1v.w};
#pragma unroll
      for (int i = 0; i < 8; ++i)
#pragma unroll
        for (int j = 0; j < 8; ++j) G[i][j] = fmaf(av[i], bv[j], G[i][j]);
    }
#pragma unroll
    for (int i = 0; i < 8; ++i)
#pragma unroll
      for (int j = 0; j < 8; ++j) rs[i] += fmaxf(G[i][j], 0.f);
  }

  __syncthreads();
  *(float4*)&rs_s[tm * 132 + tn * 8] = make_float4(rs[0], rs[1], rs[2], rs[3]);
  *(float4*)&rs_s[tm * 132 + tn * 8 + 4] = make_float4(rs[4], rs[5], rs[6], rs[7]);
  __syncthreads();
  {
    float s = 0.f;
#pragma unroll
    for (int q = 0; q < 8; ++q) s += rs_s[q * 132 + t];
    int n = nb + t;
    if (n < NN) {
      float* dst = (z == 0) ? dd0 : dd1;
      dst[b * NN + n] = s;   // partial sum (rsqrt applied in K3)
    }
  }
}

// ---------------- K3: y[b,n,c] = d[n] * sum_m relu(nv.nv) d[m] xs[m,c] (m-half) --------
// grid (7, BB, 2); 128 threads; stage1 8n x 4m, stage2 8n x 8c (all threads active)
__global__ __launch_bounds__(128) void k3_agg(const float* __restrict__ nvT_g,
                                              const float* __restrict__ dd0,
                                              const float* __restrict__ dd1,
                                              const float* __restrict__ xs_g,
                                              float* __restrict__ yr0,
                                              float* __restrict__ yr1) {
  int nt = blockIdx.x, b = blockIdx.y, z = blockIdx.z;
  int t = threadIdx.x;
  __shared__ __align__(16) float nvn[EE * 132];   // [e][nl<128]   5.3 KB
  __shared__ __align__(16) float nvm[EE * 36];    // [e][ml<32]    1.4 KB
  __shared__ __align__(16) float AsT[32 * 132];   // [ml][nl]     16.9 KB
  __shared__ __align__(16) float xs_s[32 * 72];   // [ml][c<72]    9.2 KB
  __shared__ float ddn[128];
  __shared__ float ddm[32];
  int nb = nt * 128;
  float* __restrict__ yr = (z == 0) ? yr0 : yr1;

  for (int idx = t; idx < EE * 128; idx += 128) {
    int e = idx >> 7, nl = idx & 127;
    int n = nb + nl;
    nvn[e * 132 + nl] = (n < NN) ? nvT_g[(b * EE + e) * NN + n] : 0.f;
  }
  {
    int n = nb + t;
    ddn[t] = (n < NN) ? rsqrtf(dd0[b * NN + n] + dd1[b * NN + n]) : 0.f;
  }

  int tn = t & 15;             // shared by stage1 (8n) and stage2 (8n)
  int tm = t >> 4;             // stage1: 8 groups x 4m
  int tc = t >> 4;             // stage2: 8 groups x 8c
  float acc[8][8];
#pragma unroll
  for (int i = 0; i < 8; ++i)
#pragma unroll
    for (int j = 0; j < 8; ++j) acc[i][j] = 0.f;
  float acc_e[8] = {0.f, 0.f, 0.f, 0.f, 0.f, 0.f, 0.f, 0.f};  // c=64+tc (tc<2)

  for (int s5 = 0; s5 < 14; ++s5) {
    int mb = (z * 14 + s5) * 32;
    __syncthreads();  // prev stage2 done with nvm/xs_s/AsT
    for (int idx = t; idx < EE * 32; idx += 128) {
      int e = idx >> 5, ml = idx & 31;
      int m = mb + ml;
      nvm[e * 36 + ml] = (m < NN) ? nvT_g[(b * EE + e) * NN + m] : 0.f;
    }
    if (t < 32) {
      int m = mb + t;
      ddm[t] = (m < NN) ? rsqrtf(dd0[b * NN + m] + dd1[b * NN + m]) : 0.f;
    }
    for (int idx = t; idx < 32 * CC; idx += 128) {
      int ml = idx / CC, c = idx - ml * CC;
      int m = mb + ml;
      xs_s[ml * 72 + c] = (m < NN) ? xs_g[(b * NN + m) * CC + c] : 0.f;
    }
    for (int idx = t; idx < 32 * 6; idx += 128) {
      int ml = idx / 6, c = CC + (idx - ml * 6);
      xs_s[ml * 72 + c] = 0.f;
    }
    __syncthreads();

    // stage 1: A tile (128n x 32m), 8n x 4m per thread, ALL 128 threads
    {
      float G[8][4];
#pragma unroll
      for (int i = 0; i < 8; ++i)
#pragma unroll
        for (int j = 0; j < 4; ++j) G[i][j] = 0.f;
#pragma unroll
      for (int e = 0; e < EE; ++e) {
        float4 a0 = *(const float4*)&nvn[e * 132 + tn * 8];
        float4 a1 = *(const float4*)&nvn[e * 132 + tn * 8 + 4];
        float4 bm = *(const float4*)&nvm[e * 36 + tm * 4];
        float av[8] = {a0.x, a0.y, a0.z, a0.w, a1.x, a1.y, a1.z, a1.w};
        float bv[4] = {bm.x, bm.y, bm.z, bm.w};
#pragma unroll
        for (int i = 0; i < 8; ++i)
#pragma unroll
          for (int j = 0; j < 4; ++j) G[i][j] = fmaf(av[i], bv[j], G[i][j]);
      }
#pragma unroll
      for (int j = 0; j < 4; ++j) {
        int ml = tm * 4 + j;
        float dm = ddm[ml];
        float4 v0 = make_float4(fmaxf(G[0][j], 0.f) * dm, fmaxf(G[1][j], 0.f) * dm,
                                fmaxf(G[2][j], 0.f) * dm, fmaxf(G[3][j], 0.f) * dm);
        float4 v1 = make_float4(fmaxf(G[4][j], 0.f) * dm, fmaxf(G[5][j], 0.f) * dm,
                                fmaxf(G[6][j], 0.f) * dm, fmaxf(G[7][j], 0.f) * dm);
        *(float4*)&AsT[ml * 132 + tn * 8] = v0;
        *(float4*)&AsT[ml * 132 + tn * 8 + 4] = v1;
      }
    }
    __syncthreads();

    // stage 2: acc[8n][8c] += A[n][m] * xs[m][c], ALL 128 threads
#pragma unroll 4
    for (int ml = 0; ml < 32; ++ml) {
      float4 A0 = *(const float4*)&AsT[ml * 132 + tn * 8];
      float4 A1 = *(const float4*)&AsT[ml * 132 + tn * 8 + 4];
      float4 X0 = *(const float4*)&xs_s[ml * 72 + tc * 8];
      float4 X1 = *(const float4*)&xs_s[ml * 72 + tc * 8 + 4];
      float av[8] = {A0.x, A0.y, A0.z, A0.w, A1.x, A1.y, A1.z, A1.w};
      float xv[8] = {X0.x, X0.y, X0.z, X0.w, X1.x, X1.y, X1.z, X1.w};
#pragma unroll
      for (int i = 0; i < 8; ++i)
#pragma unroll
        for (int j = 0; j < 8; ++j) acc[i][j] = fmaf(av[i], xv[j], acc[i][j]);
      if (tc < 2) {  // ride-along: c = 64+tc reusing A fragment
        float xe = xs_s[ml * 72 + 64 + tc];
#pragma unroll
        for (int i = 0; i < 8; ++i) acc_e[i] = fmaf(av[i], xe, acc_e[i]);
      }
    }
  }

#pragma unroll
  for (int i = 0; i < 8; ++i) {
    int n = nb + tn * 8 + i;
    if (n < NN) {
      float dn = ddn[tn * 8 + i];
      size_t base = (size_t)(b * NN + n) * CC;
      float4 o0 = make_float4(acc[i][0] * dn, acc[i][1] * dn, acc[i][2] * dn, acc[i][3] * dn);
      float4 o1 = make_float4(acc[i][4] * dn, acc[i][5] * dn, acc[i][6] * dn, acc[i][7] * dn);
      *(float4*)&yr[base + tc * 8] = o0;
      *(float4*)&yr[base + tc * 8 + 4] = o1;
      if (tc < 2) yr[base + 64 + tc] = acc_e[i] * dn;
    }
  }
}

// ---------------- K4: per-node weight contraction + GRU epilogue ----------------
// out_pre[o] = bias + sum_i xs_i*(W0+W1)[i][o] - y_i*W1[i][o]   (fold of L = I - Anorm)
template<int OTOT, bool GATE>
__global__ __launch_bounds__(256) void k4_out(
    const float* __restrict__ emb, const float* __restrict__ wpool,
    const float* __restrict__ bpool, const float* __restrict__ xs_g,
    const float* __restrict__ yr0, const float* __restrict__ yr1,
    float* __restrict__ zr_w,
    const float* __restrict__ state, const float* __restrict__ zr_r,
    float* __restrict__ out) {
  int n = blockIdx.x, t = threadIdx.x;
  int o_off = blockIdx.y * 64;
  __shared__ __align__(16) float W0s[CC * 64];
  __shared__ __align__(16) float W1s[CC * 64];
  __shared__ __align__(16) float xsT[CC * 36];
  __shared__ __align__(16) float yrT[CC * 36];
  __shared__ float bias_s[64];
  __shared__ float emb_s[EE];

  if (t < EE) emb_s[t] = emb[n * EE + t];
  __syncthreads();

  for (int idx = t; idx < CC * 64; idx += 256) {
    int i = idx >> 6, o = idx & 63;
    float s0 = 0.f, s1 = 0.f;
#pragma unroll
    for (int e = 0; e < EE; ++e) {
      float em = emb_s[e];
      s0 = fmaf(em, wpool[((e * 2 + 0) * CC + i) * OTOT + o_off + o], s0);
      s1 = fmaf(em, wpool[((e * 2 + 1) * CC + i) * OTOT + o_off + o], s1);
    }
    W0s[idx] = s0 + s1;  // W0 + W1
    W1s[idx] = s1;
  }
  if (t < 64) {
    float s = 0.f;
#pragma unroll
    for (int e = 0; e < EE; ++e) s = fmaf(emb_s[e], bpool[e * OTOT + o_off + t], s);
    bias_s[t] = s;
  }

  for (int bp = 0; bp < 2; ++bp) {
    __syncthreads();
    for (int idx = t; idx < 32 * CC; idx += 256) {
      int bl = idx / CC, i = idx - bl * CC;
      int bb = bp * 32 + bl;
      size_t q = (size_t)(bb * NN + n) * CC + i;
      xsT[i * 36 + bl] = xs_g[q];
      yrT[i * 36 + bl] = yr0[q] + yr1[q];
    }
    __syncthreads();

    if (t < 64) {
      int og = t & 7, bg = t >> 3;
      int o0 = og * 8, bl0 = bg * 4;
      float acc[8][4];
#pragma unroll
      for (int oi = 0; oi < 8; ++oi)
#pragma unroll
        for (int bj = 0; bj < 4; ++bj) acc[oi][bj] = bias_s[o0 + oi];
      for (int i = 0; i < CC; ++i) {
        float4 w0a = *(const float4*)&W0s[i * 64 + o0];
        float4 w0b = *(const float4*)&W0s[i * 64 + o0 + 4];
        float4 w1a = *(const float4*)&W1s[i * 64 + o0];
        float4 w1b = *(const float4*)&W1s[i * 64 + o0 + 4];
        float4 xv4 = *(const float4*)&xsT[i * 36 + bl0];
        float4 yv4 = *(const float4*)&yrT[i * 36 + bl0];
        float w0[8] = {w0a.x, w0a.y, w0a.z, w0a.w, w0b.x, w0b.y, w0b.z, w0b.w};
        float w1[8] = {w1a.x, w1a.y, w1a.z, w1a.w, w1b.x, w1b.y, w1b.z, w1b.w};
        float xv[4] = {xv4.x, xv4.y, xv4.z, xv4.w};
        float nyv[4] = {-yv4.x, -yv4.y, -yv4.z, -yv4.w};
#pragma unroll
        for (int oi = 0; oi < 8; ++oi)
#pragma unroll
          for (int bj = 0; bj < 4; ++bj) {
            acc[oi][bj] = fmaf(w0[oi], xv[bj], acc[oi][bj]);
            acc[oi][bj] = fmaf(w1[oi], nyv[bj], acc[oi][bj]);
          }
      }
#pragma unroll
      for (int oi = 0; oi < 8; ++oi) {
        int o = o_off + o0 + oi;
#pragma unroll
        for (int bj = 0; bj < 4; ++bj) {
          int bb = bp * 32 + bl0 + bj;
          float v = acc[oi][bj];
          if (GATE) {
            zr_w[(bb * NN + n) * 128 + o] = sigmoidf_(v);
          } else {
            float hc = tanhf(v);
            float r = zr_r[(bb * NN + n) * 128 + 64 + o];
            float st = state[(bb * NN + n) * 64 + o];
            out[(bb * NN + n) * 64 + o] = fmaf(r, st - hc, hc);  // r*st + (1-r)*hc
          }
        }
      }
    }
  }
}

extern "C" void kernel_launch(void* const* d_in, const int* in_sizes, int n_in,
                              void* d_out, int out_size, void* d_ws, size_t ws_size,
                              hipStream_t stream) {
  const float* x     = (const float*)d_in[0];
  const float* state = (const float*)d_in[1];
  const float* emb   = (const float*)d_in[2];
  const float* tme   = (const float*)d_in[3];
  const float* day   = (const float*)d_in[4];
  const float* spd   = (const float*)d_in[5];
  const float* occ   = (const float*)d_in[6];
  const float* gwp   = (const float*)d_in[7];
  const float* gbp   = (const float*)d_in[8];
  const float* gw1   = (const float*)d_in[9];
  const float* gb1   = (const float*)d_in[10];
  const float* gw2   = (const float*)d_in[11];
  const float* gb2   = (const float*)d_in[12];
  const float* gw3   = (const float*)d_in[13];
  const float* gb3   = (const float*)d_in[14];
  const float* uwp   = (const float*)d_in[15];
  const float* ubp   = (const float*)d_in[16];
  const float* uw1   = (const float*)d_in[17];
  const float* ub1   = (const float*)d_in[18];
  const float* uw2   = (const float*)d_in[19];
  const float* ub2   = (const float*)d_in[20];
  const float* uw3   = (const float*)d_in[21];
  const float* ub3   = (const float*)d_in[22];

  float* ws  = (float*)d_ws;
  float* xs  = ws;                             // B*N*66  = 3,729,792
  float* nvT = xs + (size_t)BB * NN * CC;      // B*10*N  =   565,120
  float* dd0 = nvT + (size_t)BB * EE * NN;     // B*N     =    56,512
  float* dd1 = dd0 + (size_t)BB * NN;          // B*N     =    56,512
  float* yr0 = dd1 + (size_t)BB * NN;          // B*N*66  = 3,729,792
  float* yr1 = yr0 + (size_t)BB * NN * CC;     // B*N*66  = 3,729,792
  float* zr  = yr1 + (size_t)BB * NN * CC;     // B*N*128 = 7,233,536
  // total ~19.1M floats = 76.4 MB

  dim3 b256(256), b128(128);
  dim3 gK1((BB * NN + 255) / 256);
  dim3 gK23(7, BB, 2);
  dim3 gK4g(NN, 2), gK4u(NN, 1);

  // phase A (gate)
  k1_hyper<0><<<gK1, b256, 0, stream>>>(x, state, zr, emb, tme, day, spd, occ,
                                        gw1, gb1, gw2, gb2, gw3, gb3, xs, nvT);
  k2_deg<<<gK23, b128, 0, stream>>>(nvT, dd0, dd1);
  k3_agg<<<gK23, b128, 0, stream>>>(nvT, dd0, dd1, xs, yr0, yr1);
  k4_out<128, true><<<gK4g, b256, 0, stream>>>(emb, gwp, gbp, xs, yr0, yr1, zr,
                                               nullptr, nullptr, nullptr);
  // phase B (update)
  k1_hyper<1><<<gK1, b256, 0, stream>>>(x, state, zr, emb, tme, day, spd, occ,
                                        uw1, ub1, uw2, ub2, uw3, ub3, xs, nvT);
  k2_deg<<<gK23, b128, 0, stream>>>(nvT, dd0, dd1);
  k3_agg<<<gK23, b128, 0, stream>>>(nvT, dd0, dd1, xs, yr0, yr1);
  k4_out<64, false><<<gK4u, b256, 0, stream>>>(emb, uwp, ubp, xs, yr0, yr1, nullptr,
                                               state, zr, (float*)d_out);
}

// Round 3
// 713.817 us; speedup vs baseline: 1.3502x; 1.1489x over previous
//
#include <hip/hip_runtime.h>
#include <cmath>

#define BB 64
#define NN 883
#define EE 10
#define CC 66

__device__ __forceinline__ float sigmoidf_(float v) { return 1.f / (1.f + expf(-v)); }

// ---------------- K1: concat + hyper-MLP + nodevec (stored transposed) ----------------
template<int PHASE>
__global__ __launch_bounds__(256) void k1_hyper(
    const float* __restrict__ x, const float* __restrict__ state,
    const float* __restrict__ zr, const float* __restrict__ emb,
    const float* __restrict__ tme, const float* __restrict__ day,
    const float* __restrict__ spd, const float* __restrict__ occ,
    const float* __restrict__ w1, const float* __restrict__ b1,
    const float* __restrict__ w2, const float* __restrict__ b2,
    const float* __restrict__ w3, const float* __restrict__ b3,
    float* __restrict__ xs_g, float* __restrict__ nvT_g) {
  int bn = blockIdx.x * 256 + threadIdx.x;
  if (bn >= BB * NN) return;
  int b = bn / NN, n = bn - b * NN;

  float xsr[CC];
  xsr[0] = x[bn * 2 + 0];
  xsr[1] = x[bn * 2 + 1];
#pragma unroll
  for (int j = 0; j < 64; ++j) {
    float s = state[bn * 64 + j];
    if (PHASE == 1) s *= zr[bn * 128 + j];   // z = first half of sigmoid(z_r)
    xsr[2 + j] = s;
  }
#pragma unroll
  for (int c = 0; c < CC; ++c) xs_g[bn * CC + c] = xsr[c];

  float h1[16];
#pragma unroll
  for (int j = 0; j < 16; ++j) h1[j] = b1[j];
#pragma unroll
  for (int i = 0; i < CC; ++i) {
    float xv = xsr[i];
#pragma unroll
    for (int j = 0; j < 16; ++j) h1[j] = fmaf(xv, w1[i * 16 + j], h1[j]);
  }
#pragma unroll
  for (int j = 0; j < 16; ++j) h1[j] = sigmoidf_(h1[j]);

  float h2[2];
#pragma unroll
  for (int j = 0; j < 2; ++j) {
    float s = b2[j];
#pragma unroll
    for (int i = 0; i < 16; ++i) s = fmaf(h1[i], w2[i * 2 + j], s);
    h2[j] = sigmoidf_(s);
  }

#pragma unroll
  for (int e = 0; e < EE; ++e) {
    float f = b3[e] + h2[0] * w3[e] + h2[1] * w3[EE + e];
    int be = bn * EE + e;
    float dyn = emb[n * EE + e] * tme[be] * day[be] * spd[be] * occ[be];
    nvT_g[(b * EE + e) * NN + n] = tanhf(dyn * f);  // transposed: [b][e][n]
  }
}

// ---------------- K2: partial rowsum of relu(nv nv^T) over an m-quarter ----------------
// grid (7, BB, 4); 128 threads; 8n x 8m per thread
__global__ __launch_bounds__(128) void k2_deg(const float* __restrict__ nvT_g,
                                              float* __restrict__ dd0,
                                              float* __restrict__ dd1,
                                              float* __restrict__ dd2,
                                              float* __restrict__ dd3) {
  int nt = blockIdx.x, b = blockIdx.y, z = blockIdx.z;
  int t = threadIdx.x;
  __shared__ __align__(16) float nvn[EE * 132];   // [e][nl<128]
  __shared__ __align__(16) float nvm[EE * 68];    // [e][ml<64]
  __shared__ __align__(16) float rs_s[8 * 132];
  int nb = nt * 128;

  for (int idx = t; idx < EE * 128; idx += 128) {
    int e = idx >> 7, nl = idx & 127;
    int n = nb + nl;
    nvn[e * 132 + nl] = (n < NN) ? nvT_g[(b * EE + e) * NN + n] : 0.f;
  }

  int tn = t & 15, tm = t >> 4;  // 16 n-groups(8n) x 8 m-groups(8m)
  float rs[8] = {0.f, 0.f, 0.f, 0.f, 0.f, 0.f, 0.f, 0.f};

  for (int s5 = 0; s5 < 4; ++s5) {
    int mb = z * 256 + s5 * 64;
    __syncthreads();
    for (int idx = t; idx < EE * 64; idx += 128) {
      int e = idx >> 6, ml = idx & 63;
      int m = mb + ml;
      nvm[e * 68 + ml] = (m < NN) ? nvT_g[(b * EE + e) * NN + m] : 0.f;
    }
    __syncthreads();

    float G[8][8];
#pragma unroll
    for (int i = 0; i < 8; ++i)
#pragma unroll
      for (int j = 0; j < 8; ++j) G[i][j] = 0.f;
#pragma unroll
    for (int e = 0; e < EE; ++e) {
      float4 a0 = *(const float4*)&nvn[e * 132 + tn * 8];
      float4 a1 = *(const float4*)&nvn[e * 132 + tn * 8 + 4];
      float4 b0 = *(const float4*)&nvm[e * 68 + tm * 8];
      float4 b1v = *(const float4*)&nvm[e * 68 + tm * 8 + 4];
      float av[8] = {a0.x, a0.y, a0.z, a0.w, a1.x, a1.y, a1.z, a1.w};
      float bv[8] = {b0.x, b0.y, b0.z, b0.w, b1v.x, b1v.y, b1v.z, b1v.w};
#pragma unroll
      for (int i = 0; i < 8; ++i)
#pragma unroll
        for (int j = 0; j < 8; ++j) G[i][j] = fmaf(av[i], bv[j], G[i][j]);
    }
#pragma unroll
    for (int i = 0; i < 8; ++i)
#pragma unroll
      for (int j = 0; j < 8; ++j) rs[i] += fmaxf(G[i][j], 0.f);
  }

  __syncthreads();
  *(float4*)&rs_s[tm * 132 + tn * 8] = make_float4(rs[0], rs[1], rs[2], rs[3]);
  *(float4*)&rs_s[tm * 132 + tn * 8 + 4] = make_float4(rs[4], rs[5], rs[6], rs[7]);
  __syncthreads();
  {
    float s = 0.f;
#pragma unroll
    for (int q = 0; q < 8; ++q) s += rs_s[q * 132 + t];
    int n = nb + t;
    if (n < NN) {
      float* dst = (z == 0) ? dd0 : (z == 1) ? dd1 : (z == 2) ? dd2 : dd3;
      dst[b * NN + n] = s;   // partial sum (rsqrt applied in K3)
    }
  }
}

// ---------------- K3: y[b,n,c] = d[n] * sum_m relu(nv.nv) d[m] xs[m,c] (m-quarter) ----
// grid (7, BB, 4); 128 threads; m-tile 16; stage1 8n x 2m, stage2 8n x 8c
__global__ __launch_bounds__(128) void k3_agg(const float* __restrict__ nvT_g,
                                              const float* __restrict__ dd0,
                                              const float* __restrict__ dd1,
                                              const float* __restrict__ dd2,
                                              const float* __restrict__ dd3,
                                              const float* __restrict__ xs_g,
                                              float* __restrict__ yr0,
                                              float* __restrict__ yr1,
                                              float* __restrict__ yr2,
                                              float* __restrict__ yr3) {
  int nt = blockIdx.x, b = blockIdx.y, z = blockIdx.z;
  int t = threadIdx.x;
  __shared__ __align__(16) float nvn[EE * 132];   // 5.3 KB
  __shared__ __align__(16) float nvm[EE * 20];    // 0.8 KB
  __shared__ __align__(16) float AsT[16 * 132];   // 8.4 KB  [ml][nl]
  __shared__ __align__(16) float xs_s[16 * 72];   // 4.6 KB  [ml][c]
  __shared__ float ddn[128];
  __shared__ float ddm[16];
  int nb = nt * 128;
  float* __restrict__ yr = (z == 0) ? yr0 : (z == 1) ? yr1 : (z == 2) ? yr2 : yr3;

  for (int idx = t; idx < EE * 128; idx += 128) {
    int e = idx >> 7, nl = idx & 127;
    int n = nb + nl;
    nvn[e * 132 + nl] = (n < NN) ? nvT_g[(b * EE + e) * NN + n] : 0.f;
  }
  {
    int n = nb + t;
    ddn[t] = (n < NN) ? rsqrtf(dd0[b * NN + n] + dd1[b * NN + n] +
                               dd2[b * NN + n] + dd3[b * NN + n]) : 0.f;
  }

  int tn = t & 15;   // 16 groups of 8n (stage1 + stage2)
  int tg = t >> 4;   // stage1: 8 groups x 2m; stage2: 8 groups x 8c
  float acc[8][8];
#pragma unroll
  for (int i = 0; i < 8; ++i)
#pragma unroll
    for (int j = 0; j < 8; ++j) acc[i][j] = 0.f;
  float acc_e[8] = {0.f, 0.f, 0.f, 0.f, 0.f, 0.f, 0.f, 0.f};  // c=64+tg for tg<2

  for (int s5 = 0; s5 < 14; ++s5) {
    int mb = z * 224 + s5 * 16;
    __syncthreads();
    // fills
    if (t < EE * 16) {  // 160 lanes worth -> two rounds
      int e = t >> 4, ml = t & 15;
      int m = mb + ml;
      nvm[e * 20 + ml] = (m < NN) ? nvT_g[(b * EE + e) * NN + m] : 0.f;
    }
    if (t >= 96 && t < 128) {  // remaining e=8,9 rows (idx 128..159)
      int idx = t + 32;
      int e = idx >> 4, ml = idx & 15;
      int m = mb + ml;
      nvm[e * 20 + ml] = (m < NN) ? nvT_g[(b * EE + e) * NN + m] : 0.f;
    }
    if (t < 16) {
      int m = mb + t;
      ddm[t] = (m < NN) ? rsqrtf(dd0[b * NN + m] + dd1[b * NN + m] +
                                 dd2[b * NN + m] + dd3[b * NN + m]) : 0.f;
    }
    for (int idx = t; idx < 16 * CC; idx += 128) {
      int ml = idx / CC, c = idx - ml * CC;
      int m = mb + ml;
      xs_s[ml * 72 + c] = (m < NN) ? xs_g[(b * NN + m) * CC + c] : 0.f;
    }
    if (t < 96) {  // zero the 6-col pad: 16*6
      int ml = t / 6, c = CC + (t - ml * 6);
      xs_s[ml * 72 + c] = 0.f;
    }
    __syncthreads();

    // stage 1: A tile (128n x 16m), 8n x 2m per thread
    {
      float G[8][2];
#pragma unroll
      for (int i = 0; i < 8; ++i) { G[i][0] = 0.f; G[i][1] = 0.f; }
#pragma unroll
      for (int e = 0; e < EE; ++e) {
        float4 a0 = *(const float4*)&nvn[e * 132 + tn * 8];
        float4 a1 = *(const float4*)&nvn[e * 132 + tn * 8 + 4];
        float2 bm = *(const float2*)&nvm[e * 20 + tg * 2];
        float av[8] = {a0.x, a0.y, a0.z, a0.w, a1.x, a1.y, a1.z, a1.w};
#pragma unroll
        for (int i = 0; i < 8; ++i) {
          G[i][0] = fmaf(av[i], bm.x, G[i][0]);
          G[i][1] = fmaf(av[i], bm.y, G[i][1]);
        }
      }
#pragma unroll
      for (int j = 0; j < 2; ++j) {
        int ml = tg * 2 + j;
        float dm = ddm[ml];
        float4 v0 = make_float4(fmaxf(G[0][j], 0.f) * dm, fmaxf(G[1][j], 0.f) * dm,
                                fmaxf(G[2][j], 0.f) * dm, fmaxf(G[3][j], 0.f) * dm);
        float4 v1 = make_float4(fmaxf(G[4][j], 0.f) * dm, fmaxf(G[5][j], 0.f) * dm,
                                fmaxf(G[6][j], 0.f) * dm, fmaxf(G[7][j], 0.f) * dm);
        *(float4*)&AsT[ml * 132 + tn * 8] = v0;
        *(float4*)&AsT[ml * 132 + tn * 8 + 4] = v1;
      }
    }
    __syncthreads();

    // stage 2: acc[8n][8c] += A[n][m] * xs[m][c]
#pragma unroll 4
    for (int ml = 0; ml < 16; ++ml) {
      float4 A0 = *(const float4*)&AsT[ml * 132 + tn * 8];
      float4 A1 = *(const float4*)&AsT[ml * 132 + tn * 8 + 4];
      float4 X0 = *(const float4*)&xs_s[ml * 72 + tg * 8];
      float4 X1 = *(const float4*)&xs_s[ml * 72 + tg * 8 + 4];
      float av[8] = {A0.x, A0.y, A0.z, A0.w, A1.x, A1.y, A1.z, A1.w};
      float xv[8] = {X0.x, X0.y, X0.z, X0.w, X1.x, X1.y, X1.z, X1.w};
#pragma unroll
      for (int i = 0; i < 8; ++i)
#pragma unroll
        for (int j = 0; j < 8; ++j) acc[i][j] = fmaf(av[i], xv[j], acc[i][j]);
      if (tg < 2) {  // ride-along: c = 64+tg reusing A fragment
        float xe = xs_s[ml * 72 + 64 + tg];
#pragma unroll
        for (int i = 0; i < 8; ++i) acc_e[i] = fmaf(av[i], xe, acc_e[i]);
      }
    }
  }

#pragma unroll
  for (int i = 0; i < 8; ++i) {
    int n = nb + tn * 8 + i;
    if (n < NN) {
      float dn = ddn[tn * 8 + i];
      size_t base = (size_t)(b * NN + n) * CC;
      float4 o0 = make_float4(acc[i][0] * dn, acc[i][1] * dn, acc[i][2] * dn, acc[i][3] * dn);
      float4 o1 = make_float4(acc[i][4] * dn, acc[i][5] * dn, acc[i][6] * dn, acc[i][7] * dn);
      *(float4*)&yr[base + tg * 8] = o0;
      *(float4*)&yr[base + tg * 8 + 4] = o1;
      if (tg < 2) yr[base + 64 + tg] = acc_e[i] * dn;
    }
  }
}

// ---------------- K4: per-node weight contraction + GRU epilogue ----------------
// out_pre[o] = bias + sum_i xs_i*(W0+W1)[i][o] - y_i*W1[i][o]   (fold of L = I - Anorm)
template<int OTOT, bool GATE>
__global__ __launch_bounds__(256) void k4_out(
    const float* __restrict__ emb, const float* __restrict__ wpool,
    const float* __restrict__ bpool, const float* __restrict__ xs_g,
    const float* __restrict__ yr0, const float* __restrict__ yr1,
    const float* __restrict__ yr2, const float* __restrict__ yr3,
    float* __restrict__ zr_w,
    const float* __restrict__ state, const float* __restrict__ zr_r,
    float* __restrict__ out) {
  int n = blockIdx.x, t = threadIdx.x;
  int o_off = blockIdx.y * 64;
  __shared__ __align__(16) float W0s[CC * 64];
  __shared__ __align__(16) float W1s[CC * 64];
  __shared__ __align__(16) float xsT[CC * 36];
  __shared__ __align__(16) float yrT[CC * 36];
  __shared__ float bias_s[64];
  __shared__ float emb_s[EE];

  if (t < EE) emb_s[t] = emb[n * EE + t];
  __syncthreads();

  for (int idx = t; idx < CC * 64; idx += 256) {
    int i = idx >> 6, o = idx & 63;
    float s0 = 0.f, s1 = 0.f;
#pragma unroll
    for (int e = 0; e < EE; ++e) {
      float em = emb_s[e];
      s0 = fmaf(em, wpool[((e * 2 + 0) * CC + i) * OTOT + o_off + o], s0);
      s1 = fmaf(em, wpool[((e * 2 + 1) * CC + i) * OTOT + o_off + o], s1);
    }
    W0s[idx] = s0 + s1;  // W0 + W1
    W1s[idx] = s1;
  }
  if (t < 64) {
    float s = 0.f;
#pragma unroll
    for (int e = 0; e < EE; ++e) s = fmaf(emb_s[e], bpool[e * OTOT + o_off + t], s);
    bias_s[t] = s;
  }

  int og = t & 7, bg = t >> 3;       // 8 o-groups x 32 b-lanes — ALL 256 threads
  int o0 = og * 8;

  for (int bp = 0; bp < 2; ++bp) {
    __syncthreads();
    for (int idx = t; idx < 32 * CC; idx += 256) {
      int bl = idx / CC, i = idx - bl * CC;
      int bb = bp * 32 + bl;
      size_t q = (size_t)(bb * NN + n) * CC + i;
      xsT[i * 36 + bl] = xs_g[q];
      yrT[i * 36 + bl] = yr0[q] + yr1[q] + yr2[q] + yr3[q];
    }
    __syncthreads();

    float acc[8];
#pragma unroll
    for (int oi = 0; oi < 8; ++oi) acc[oi] = bias_s[o0 + oi];
    for (int i = 0; i < CC; ++i) {
      float4 w0a = *(const float4*)&W0s[i * 64 + o0];
      float4 w0b = *(const float4*)&W0s[i * 64 + o0 + 4];
      float4 w1a = *(const float4*)&W1s[i * 64 + o0];
      float4 w1b = *(const float4*)&W1s[i * 64 + o0 + 4];
      float xv = xsT[i * 36 + bg];
      float nyv = -yrT[i * 36 + bg];
      float w0[8] = {w0a.x, w0a.y, w0a.z, w0a.w, w0b.x, w0b.y, w0b.z, w0b.w};
      float w1[8] = {w1a.x, w1a.y, w1a.z, w1a.w, w1b.x, w1b.y, w1b.z, w1b.w};
#pragma unroll
      for (int oi = 0; oi < 8; ++oi) {
        acc[oi] = fmaf(w0[oi], xv, acc[oi]);
        acc[oi] = fmaf(w1[oi], nyv, acc[oi]);
      }
    }

    int bb = bp * 32 + bg;
#pragma unroll
    for (int oi = 0; oi < 8; ++oi) {
      int o = o_off + o0 + oi;
      float v = acc[oi];
      if (GATE) {
        zr_w[(bb * NN + n) * 128 + o] = sigmoidf_(v);
      } else {
        float hc = tanhf(v);
        float r = zr_r[(bb * NN + n) * 128 + 64 + o];
        float st = state[(bb * NN + n) * 64 + o];
        out[(bb * NN + n) * 64 + o] = fmaf(r, st - hc, hc);  // r*st + (1-r)*hc
      }
    }
  }
}

extern "C" void kernel_launch(void* const* d_in, const int* in_sizes, int n_in,
                              void* d_out, int out_size, void* d_ws, size_t ws_size,
                              hipStream_t stream) {
  const float* x     = (const float*)d_in[0];
  const float* state = (const float*)d_in[1];
  const float* emb   = (const float*)d_in[2];
  const float* tme   = (const float*)d_in[3];
  const float* day   = (const float*)d_in[4];
  const float* spd   = (const float*)d_in[5];
  const float* occ   = (const float*)d_in[6];
  const float* gwp   = (const float*)d_in[7];
  const float* gbp   = (const float*)d_in[8];
  const float* gw1   = (const float*)d_in[9];
  const float* gb1   = (const float*)d_in[10];
  const float* gw2   = (const float*)d_in[11];
  const float* gb2   = (const float*)d_in[12];
  const float* gw3   = (const float*)d_in[13];
  const float* gb3   = (const float*)d_in[14];
  const float* uwp   = (const float*)d_in[15];
  const float* ubp   = (const float*)d_in[16];
  const float* uw1   = (const float*)d_in[17];
  const float* ub1   = (const float*)d_in[18];
  const float* uw2   = (const float*)d_in[19];
  const float* ub2   = (const float*)d_in[20];
  const float* uw3   = (const float*)d_in[21];
  const float* ub3   = (const float*)d_in[22];

  float* ws  = (float*)d_ws;
  float* xs  = ws;                             // B*N*66
  float* nvT = xs + (size_t)BB * NN * CC;      // B*10*N
  float* dd0 = nvT + (size_t)BB * EE * NN;
  float* dd1 = dd0 + (size_t)BB * NN;
  float* dd2 = dd1 + (size_t)BB * NN;
  float* dd3 = dd2 + (size_t)BB * NN;
  float* yr0 = dd3 + (size_t)BB * NN;          // B*N*66 x4
  float* yr1 = yr0 + (size_t)BB * NN * CC;
  float* yr2 = yr1 + (size_t)BB * NN * CC;
  float* yr3 = yr2 + (size_t)BB * NN * CC;
  float* zr  = yr3 + (size_t)BB * NN * CC;     // B*N*128
  // total ~26.7M floats = 107 MB

  dim3 b256(256), b128(128);
  dim3 gK1((BB * NN + 255) / 256);
  dim3 gK23(7, BB, 4);
  dim3 gK4g(NN, 2), gK4u(NN, 1);

  // phase A (gate)
  k1_hyper<0><<<gK1, b256, 0, stream>>>(x, state, zr, emb, tme, day, spd, occ,
                                        gw1, gb1, gw2, gb2, gw3, gb3, xs, nvT);
  k2_deg<<<gK23, b128, 0, stream>>>(nvT, dd0, dd1, dd2, dd3);
  k3_agg<<<gK23, b128, 0, stream>>>(nvT, dd0, dd1, dd2, dd3, xs, yr0, yr1, yr2, yr3);
  k4_out<128, true><<<gK4g, b256, 0, stream>>>(emb, gwp, gbp, xs, yr0, yr1, yr2, yr3,
                                               zr, nullptr, nullptr, nullptr);
  // phase B (update)
  k1_hyper<1><<<gK1, b256, 0, stream>>>(x, state, zr, emb, tme, day, spd, occ,
                                        uw1, ub1, uw2, ub2, uw3, ub3, xs, nvT);
  k2_deg<<<gK23, b128, 0, stream>>>(nvT, dd0, dd1, dd2, dd3);
  k3_agg<<<gK23, b128, 0, stream>>>(nvT, dd0, dd1, dd2, dd3, xs, yr0, yr1, yr2, yr3);
  k4_out<64, false><<<gK4u, b256, 0, stream>>>(emb, uwp, ubp, xs, yr0, yr1, yr2, yr3,
                                               nullptr, state, zr, (float*)d_out);
}

// Round 4
// 487.044 us; speedup vs baseline: 1.9788x; 1.4656x over previous
//
#include <hip/hip_runtime.h>
#include <cmath>

#define BB 64
#define NN 883
#define NP 896      // N padded to multiple of 64
#define EE 10
#define CC 66

typedef __attribute__((ext_vector_type(8))) short bf16x8;
typedef __attribute__((ext_vector_type(4))) float f32x4;

__device__ __forceinline__ float sigmoidf_(float v) { return 1.f / (1.f + expf(-v)); }

// fp32 -> bf16 round-to-nearest-even
__device__ __forceinline__ unsigned short f2bf(float f) {
  unsigned int u = __float_as_uint(f);
  u = u + 0x7FFFu + ((u >> 16) & 1u);
  return (unsigned short)(u >> 16);
}

// ---------------- K1: concat + hyper-MLP + nodevec (bf16, e-padded to 16) ------------
template<int PHASE>
__global__ __launch_bounds__(256) void k1_hyper(
    const float* __restrict__ x, const float* __restrict__ state,
    const float* __restrict__ zr, const float* __restrict__ emb,
    const float* __restrict__ tme, const float* __restrict__ day,
    const float* __restrict__ spd, const float* __restrict__ occ,
    const float* __restrict__ w1, const float* __restrict__ b1,
    const float* __restrict__ w2, const float* __restrict__ b2,
    const float* __restrict__ w3, const float* __restrict__ b3,
    float* __restrict__ xs_g, unsigned short* __restrict__ nvP) {
  int idx = blockIdx.x * 256 + threadIdx.x;   // over BB*NP
  if (idx >= BB * NP) return;
  int b = idx / NP, n = idx - b * NP;
  if (n >= NN) {  // zero-pad row (needed so MFMA B-frags read zeros)
    *(uint4*)&nvP[(size_t)idx * 16] = make_uint4(0, 0, 0, 0);
    *(uint4*)&nvP[(size_t)idx * 16 + 8] = make_uint4(0, 0, 0, 0);
    return;
  }
  int bn = b * NN + n;

  float xsr[CC];
  xsr[0] = x[bn * 2 + 0];
  xsr[1] = x[bn * 2 + 1];
#pragma unroll
  for (int j = 0; j < 64; ++j) {
    float s = state[bn * 64 + j];
    if (PHASE == 1) s *= zr[bn * 128 + j];   // z = first half of sigmoid(z_r)
    xsr[2 + j] = s;
  }
#pragma unroll
  for (int c = 0; c < CC; ++c) xs_g[(size_t)bn * CC + c] = xsr[c];

  float h1[16];
#pragma unroll
  for (int j = 0; j < 16; ++j) h1[j] = b1[j];
#pragma unroll
  for (int i = 0; i < CC; ++i) {
    float xv = xsr[i];
#pragma unroll
    for (int j = 0; j < 16; ++j) h1[j] = fmaf(xv, w1[i * 16 + j], h1[j]);
  }
#pragma unroll
  for (int j = 0; j < 16; ++j) h1[j] = sigmoidf_(h1[j]);

  float h2[2];
#pragma unroll
  for (int j = 0; j < 2; ++j) {
    float s = b2[j];
#pragma unroll
    for (int i = 0; i < 16; ++i) s = fmaf(h1[i], w2[i * 2 + j], s);
    h2[j] = sigmoidf_(s);
  }

  unsigned short nv16[16];
#pragma unroll
  for (int e = 0; e < EE; ++e) {
    float f = b3[e] + h2[0] * w3[e] + h2[1] * w3[EE + e];
    int be = bn * EE + e;
    float dyn = emb[n * EE + e] * tme[be] * day[be] * spd[be] * occ[be];
    nv16[e] = f2bf(tanhf(dyn * f));
  }
#pragma unroll
  for (int e = EE; e < 16; ++e) nv16[e] = 0;
  unsigned int w[8];
#pragma unroll
  for (int k = 0; k < 8; ++k)
    w[k] = (unsigned int)nv16[2 * k] | ((unsigned int)nv16[2 * k + 1] << 16);
  *(uint4*)&nvP[(size_t)idx * 16]     = make_uint4(w[0], w[1], w[2], w[3]);
  *(uint4*)&nvP[(size_t)idx * 16 + 8] = make_uint4(w[4], w[5], w[6], w[7]);
}

// ---------------- K2: dd[b,n] = rowsum relu(nv nv^T) via MFMA ----------------
// grid (14, 64), 256 thr = 4 waves; wave w owns n-rows [nt*64+w*16, +16)
__global__ __launch_bounds__(256) void k2_deg(const unsigned short* __restrict__ nvP,
                                              float* __restrict__ dd) {
  int nt = blockIdx.x, b = blockIdx.y;
  int t = threadIdx.x, wid = t >> 6, lane = t & 63;
  int col = lane & 15, q = lane >> 4;
  int n16 = nt * 64 + wid * 16;

  bf16x8 anv = {0, 0, 0, 0, 0, 0, 0, 0};
  if (q < 2) anv = *(const bf16x8*)&nvP[((size_t)(b * NP + n16 + col)) * 16 + q * 8];

  float rs0 = 0.f, rs1 = 0.f, rs2 = 0.f, rs3 = 0.f;
  for (int mb = 0; mb < NP; mb += 16) {
    bf16x8 bfr = {0, 0, 0, 0, 0, 0, 0, 0};
    if (q < 2) bfr = *(const bf16x8*)&nvP[((size_t)(b * NP + mb + col)) * 16 + q * 8];
    f32x4 z = {0.f, 0.f, 0.f, 0.f};
    f32x4 g = __builtin_amdgcn_mfma_f32_16x16x32_bf16(anv, bfr, z, 0, 0, 0);
    rs0 += fmaxf(g[0], 0.f);
    rs1 += fmaxf(g[1], 0.f);
    rs2 += fmaxf(g[2], 0.f);
    rs3 += fmaxf(g[3], 0.f);
  }
  // reduce across the 16 col-lanes (xor masks < 16 keep 16-lane groups)
#pragma unroll
  for (int off = 1; off < 16; off <<= 1) {
    rs0 += __shfl_xor(rs0, off);
    rs1 += __shfl_xor(rs1, off);
    rs2 += __shfl_xor(rs2, off);
    rs3 += __shfl_xor(rs3, off);
  }
  if (col == 0) {
    int base = b * NP + n16 + q * 4;
    dd[base + 0] = rs0;
    dd[base + 1] = rs1;
    dd[base + 2] = rs2;
    dd[base + 3] = rs3;
  }
}

// ---------------- K2b: d = rsqrt(dd); xsdT[b][c][m] = bf16(d[m]*xs[m][c]) ------------
__global__ __launch_bounds__(256) void k2b_xsd(const float* __restrict__ dd,
                                               const float* __restrict__ xs_g,
                                               float* __restrict__ d_g,
                                               unsigned short* __restrict__ xsdT) {
  int mt = blockIdx.x, b = blockIdx.y, t = threadIdx.x;
  __shared__ float tile[64][67];
  __shared__ float d_s[64];
  int mb = mt * 64;
  if (t < 64) {
    int m = mb + t;
    float dv = 0.f;
    if (m < NN) dv = rsqrtf(dd[b * NP + m]);
    d_s[t] = dv;
    d_g[b * NP + m] = dv;
  }
  for (int idx = t; idx < 64 * CC; idx += 256) {
    int ml = idx / CC, c = idx - ml * CC;
    int m = mb + ml;
    tile[ml][c] = (m < NN) ? xs_g[((size_t)(b * NN + m)) * CC + c] : 0.f;
  }
  __syncthreads();
  for (int idx = t; idx < CC * 64; idx += 256) {
    int c = idx >> 6, ml = idx & 63;
    xsdT[((size_t)(b * CC) + c) * NP + mb + ml] = f2bf(tile[ml][c] * d_s[ml]);
  }
}

// ---------------- K3: y[b,n,c] = d[n] * sum_m relu(nv.nv)[n,m] * xsd[m,c] (MFMA) -----
// grid (14, 64), 256 thr = 4 waves; barrier-free main loop, wave-private LDS A-tile
__global__ __launch_bounds__(256) void k3_agg(const unsigned short* __restrict__ nvP,
                                              const float* __restrict__ d_g,
                                              const unsigned short* __restrict__ xsdT,
                                              float* __restrict__ yr) {
  int nt = blockIdx.x, b = blockIdx.y, t = threadIdx.x;
  int wid = t >> 6, lane = t & 63, col = lane & 15, q = lane >> 4;
  int n16 = nt * 64 + wid * 16;
  __shared__ __align__(16) unsigned short As[4][16 * 40];  // per-wave [n16][m32 pad40]
  unsigned short* wAs = As[wid];

  bf16x8 anv = {0, 0, 0, 0, 0, 0, 0, 0};
  if (q < 2) anv = *(const bf16x8*)&nvP[((size_t)(b * NP + n16 + col)) * 16 + q * 8];

  f32x4 acc[5];
#pragma unroll
  for (int ct = 0; ct < 5; ++ct) acc[ct] = (f32x4){0.f, 0.f, 0.f, 0.f};

  for (int mb = 0; mb < NP; mb += 32) {
    // stage 1: G1(16n x 32m) via 2 MFMAs, nv frags straight from global
    bf16x8 b0 = {0, 0, 0, 0, 0, 0, 0, 0};
    bf16x8 b1 = {0, 0, 0, 0, 0, 0, 0, 0};
    if (q < 2) {
      b0 = *(const bf16x8*)&nvP[((size_t)(b * NP + mb + col)) * 16 + q * 8];
      b1 = *(const bf16x8*)&nvP[((size_t)(b * NP + mb + 16 + col)) * 16 + q * 8];
    }
    f32x4 z = {0.f, 0.f, 0.f, 0.f};
    f32x4 g0 = __builtin_amdgcn_mfma_f32_16x16x32_bf16(anv, b0, z, 0, 0, 0);
    f32x4 g1 = __builtin_amdgcn_mfma_f32_16x16x32_bf16(anv, b1, z, 0, 0, 0);
    // relu -> bf16 -> wave-private LDS (C-layout -> A-operand layout transform)
#pragma unroll
    for (int r = 0; r < 4; ++r) {
      wAs[(q * 4 + r) * 40 + col]      = f2bf(fmaxf(g0[r], 0.f));
      wAs[(q * 4 + r) * 40 + col + 16] = f2bf(fmaxf(g1[r], 0.f));
    }
    // stage 2: A-frag from LDS, xsd B-frags straight from global
    bf16x8 afr = *(const bf16x8*)&wAs[col * 40 + q * 8];
#pragma unroll
    for (int ct = 0; ct < 5; ++ct) {
      int c = ct * 16 + col;
      bf16x8 xf = {0, 0, 0, 0, 0, 0, 0, 0};
      if (c < CC) xf = *(const bf16x8*)&xsdT[((size_t)(b * CC) + c) * NP + mb + q * 8];
      acc[ct] = __builtin_amdgcn_mfma_f32_16x16x32_bf16(afr, xf, acc[ct], 0, 0, 0);
    }
  }

  float dn[4];
#pragma unroll
  for (int r = 0; r < 4; ++r) dn[r] = d_g[b * NP + n16 + q * 4 + r];
#pragma unroll
  for (int ct = 0; ct < 5; ++ct) {
    int c = ct * 16 + col;
    if (c < CC) {
#pragma unroll
      for (int r = 0; r < 4; ++r) {
        int n = n16 + q * 4 + r;
        if (n < NN) yr[((size_t)(b * NN) + n) * CC + c] = acc[ct][r] * dn[r];
      }
    }
  }
}

// ---------------- K4: per-node weight contraction + GRU epilogue ----------------
// out_pre[o] = bias + sum_i xs_i*(W0+W1)[i][o] - y_i*W1[i][o]   (fold of L = I - Anorm)
template<int OTOT, bool GATE>
__global__ __launch_bounds__(256) void k4_out(
    const float* __restrict__ emb, const float* __restrict__ wpool,
    const float* __restrict__ bpool, const float* __restrict__ xs_g,
    const float* __restrict__ yr,
    float* __restrict__ zr_w,
    const float* __restrict__ state, const float* __restrict__ zr_r,
    float* __restrict__ out) {
  int n = blockIdx.x, t = threadIdx.x;
  int o_off = blockIdx.y * 64;
  __shared__ __align__(16) float W0s[CC * 64];
  __shared__ __align__(16) float W1s[CC * 64];
  __shared__ __align__(16) float xsT[CC * 36];
  __shared__ __align__(16) float yrT[CC * 36];
  __shared__ float bias_s[64];
  __shared__ float emb_s[EE];

  if (t < EE) emb_s[t] = emb[n * EE + t];
  __syncthreads();

  for (int idx = t; idx < CC * 64; idx += 256) {
    int i = idx >> 6, o = idx & 63;
    float s0 = 0.f, s1 = 0.f;
#pragma unroll
    for (int e = 0; e < EE; ++e) {
      float em = emb_s[e];
      s0 = fmaf(em, wpool[((e * 2 + 0) * CC + i) * OTOT + o_off + o], s0);
      s1 = fmaf(em, wpool[((e * 2 + 1) * CC + i) * OTOT + o_off + o], s1);
    }
    W0s[idx] = s0 + s1;  // W0 + W1
    W1s[idx] = s1;
  }
  if (t < 64) {
    float s = 0.f;
#pragma unroll
    for (int e = 0; e < EE; ++e) s = fmaf(emb_s[e], bpool[e * OTOT + o_off + t], s);
    bias_s[t] = s;
  }

  int og = t & 7, bg = t >> 3;       // 8 o-groups x 32 b-lanes — ALL 256 threads
  int o0 = og * 8;

  for (int bp = 0; bp < 2; ++bp) {
    __syncthreads();
    for (int idx = t; idx < 32 * CC; idx += 256) {
      int bl = idx / CC, i = idx - bl * CC;
      int bb = bp * 32 + bl;
      size_t qd = (size_t)(bb * NN + n) * CC + i;
      xsT[i * 36 + bl] = xs_g[qd];
      yrT[i * 36 + bl] = yr[qd];
    }
    __syncthreads();

    float acc[8];
#pragma unroll
    for (int oi = 0; oi < 8; ++oi) acc[oi] = bias_s[o0 + oi];
    for (int i = 0; i < CC; ++i) {
      float4 w0a = *(const float4*)&W0s[i * 64 + o0];
      float4 w0b = *(const float4*)&W0s[i * 64 + o0 + 4];
      float4 w1a = *(const float4*)&W1s[i * 64 + o0];
      float4 w1b = *(const float4*)&W1s[i * 64 + o0 + 4];
      float xv = xsT[i * 36 + bg];
      float nyv = -yrT[i * 36 + bg];
      float w0[8] = {w0a.x, w0a.y, w0a.z, w0a.w, w0b.x, w0b.y, w0b.z, w0b.w};
      float w1[8] = {w1a.x, w1a.y, w1a.z, w1a.w, w1b.x, w1b.y, w1b.z, w1b.w};
#pragma unroll
      for (int oi = 0; oi < 8; ++oi) {
        acc[oi] = fmaf(w0[oi], xv, acc[oi]);
        acc[oi] = fmaf(w1[oi], nyv, acc[oi]);
      }
    }

    int bb = bp * 32 + bg;
#pragma unroll
    for (int oi = 0; oi < 8; ++oi) {
      int o = o_off + o0 + oi;
      float v = acc[oi];
      if (GATE) {
        zr_w[(size_t)(bb * NN + n) * 128 + o] = sigmoidf_(v);
      } else {
        float hc = tanhf(v);
        float r = zr_r[(size_t)(bb * NN + n) * 128 + 64 + o];
        float st = state[(size_t)(bb * NN + n) * 64 + o];
        out[(size_t)(bb * NN + n) * 64 + o] = fmaf(r, st - hc, hc);  // r*st+(1-r)*hc
      }
    }
  }
}

extern "C" void kernel_launch(void* const* d_in, const int* in_sizes, int n_in,
                              void* d_out, int out_size, void* d_ws, size_t ws_size,
                              hipStream_t stream) {
  const float* x     = (const float*)d_in[0];
  const float* state = (const float*)d_in[1];
  const float* emb   = (const float*)d_in[2];
  const float* tme   = (const float*)d_in[3];
  const float* day   = (const float*)d_in[4];
  const float* spd   = (const float*)d_in[5];
  const float* occ   = (const float*)d_in[6];
  const float* gwp   = (const float*)d_in[7];
  const float* gbp   = (const float*)d_in[8];
  const float* gw1   = (const float*)d_in[9];
  const float* gb1   = (const float*)d_in[10];
  const float* gw2   = (const float*)d_in[11];
  const float* gb2   = (const float*)d_in[12];
  const float* gw3   = (const float*)d_in[13];
  const float* gb3   = (const float*)d_in[14];
  const float* uwp   = (const float*)d_in[15];
  const float* ubp   = (const float*)d_in[16];
  const float* uw1   = (const float*)d_in[17];
  const float* ub1   = (const float*)d_in[18];
  const float* uw2   = (const float*)d_in[19];
  const float* ub2   = (const float*)d_in[20];
  const float* uw3   = (const float*)d_in[21];
  const float* ub3   = (const float*)d_in[22];

  char* w = (char*)d_ws;
  float* xs   = (float*)w;  w += (size_t)BB * NN * CC * 4;    // 14.92 MB
  float* dd   = (float*)w;  w += (size_t)BB * NP * 4;         // 229 KB
  float* d_g  = (float*)w;  w += (size_t)BB * NP * 4;
  float* yr   = (float*)w;  w += (size_t)BB * NN * CC * 4;    // 14.92 MB
  float* zr   = (float*)w;  w += (size_t)BB * NN * 128 * 4;   // 28.93 MB
  unsigned short* nvP  = (unsigned short*)w;  w += (size_t)BB * NP * 16 * 2;  // 1.84 MB
  unsigned short* xsdT = (unsigned short*)w;  w += (size_t)BB * CC * NP * 2;  // 7.57 MB

  dim3 b256(256);
  dim3 gK1((BB * NP) / 256);      // 224
  dim3 gK2(14, BB);
  dim3 gK4g(NN, 2), gK4u(NN, 1);

  // phase A (gate)
  k1_hyper<0><<<gK1, b256, 0, stream>>>(x, state, zr, emb, tme, day, spd, occ,
                                        gw1, gb1, gw2, gb2, gw3, gb3, xs, nvP);
  k2_deg<<<gK2, b256, 0, stream>>>(nvP, dd);
  k2b_xsd<<<gK2, b256, 0, stream>>>(dd, xs, d_g, xsdT);
  k3_agg<<<gK2, b256, 0, stream>>>(nvP, d_g, xsdT, yr);
  k4_out<128, true><<<gK4g, b256, 0, stream>>>(emb, gwp, gbp, xs, yr, zr,
                                               nullptr, nullptr, nullptr);
  // phase B (update)
  k1_hyper<1><<<gK1, b256, 0, stream>>>(x, state, zr, emb, tme, day, spd, occ,
                                        uw1, ub1, uw2, ub2, uw3, ub3, xs, nvP);
  k2_deg<<<gK2, b256, 0, stream>>>(nvP, dd);
  k2b_xsd<<<gK2, b256, 0, stream>>>(dd, xs, d_g, xsdT);
  k3_agg<<<gK2, b256, 0, stream>>>(nvP, d_g, xsdT, yr);
  k4_out<64, false><<<gK4u, b256, 0, stream>>>(emb, uwp, ubp, xs, yr,
                                               nullptr, state, zr, (float*)d_out);
}

// Round 5
// 426.024 us; speedup vs baseline: 2.2623x; 1.1432x over previous
//
#include <hip/hip_runtime.h>
#include <cmath>

#define BB 64
#define NN 883
#define NP 896      // N padded to multiple of 64
#define EE 10
#define CC 66
#define KP 160      // A'/W' padded K: [0,66)=xs|W0+W1, [80,146)=-d*y|W1, rest 0

typedef __attribute__((ext_vector_type(8))) short bf16x8;
typedef __attribute__((ext_vector_type(4))) float f32x4;

__device__ __forceinline__ float sigmoidf_(float v) { return 1.f / (1.f + expf(-v)); }

// fp32 -> bf16 round-to-nearest-even
__device__ __forceinline__ unsigned short f2bf(float f) {
  unsigned int u = __float_as_uint(f);
  u = u + 0x7FFFu + ((u >> 16) & 1u);
  return (unsigned short)(u >> 16);
}
__device__ __forceinline__ float bf2f(unsigned short h) {
  return __uint_as_float(((unsigned int)h) << 16);
}

// ---------------- K1: concat + hyper-MLP + nodevec; writes Acat[0..79] + nvP --------
template<int PHASE>
__global__ __launch_bounds__(256) void k1_hyper(
    const float* __restrict__ x, const float* __restrict__ state,
    const float* __restrict__ zr, const float* __restrict__ emb,
    const float* __restrict__ tme, const float* __restrict__ day,
    const float* __restrict__ spd, const float* __restrict__ occ,
    const float* __restrict__ w1, const float* __restrict__ b1,
    const float* __restrict__ w2, const float* __restrict__ b2,
    const float* __restrict__ w3, const float* __restrict__ b3,
    unsigned short* __restrict__ Acat, unsigned short* __restrict__ nvP) {
  int idx = blockIdx.x * 256 + threadIdx.x;   // over BB*NP
  if (idx >= BB * NP) return;
  int b = idx / NP, n = idx - b * NP;
  if (n >= NN) {  // zero-pad row of nvP (MFMA B-frags must read zeros)
    *(uint4*)&nvP[(size_t)idx * 16] = make_uint4(0, 0, 0, 0);
    *(uint4*)&nvP[(size_t)idx * 16 + 8] = make_uint4(0, 0, 0, 0);
    return;
  }
  int bn = b * NN + n;

  float xsr[CC];
  xsr[0] = x[bn * 2 + 0];
  xsr[1] = x[bn * 2 + 1];
#pragma unroll
  for (int j = 0; j < 64; ++j) {
    float s = state[bn * 64 + j];
    if (PHASE == 1) s *= zr[(size_t)bn * 128 + j];   // z = first half of sigmoid(z_r)
    xsr[2 + j] = s;
  }
  // write xs (bf16) into Acat slots [0,80) (66 real + 14 zero pad)
  {
    unsigned short a16[80];
#pragma unroll
    for (int c = 0; c < CC; ++c) a16[c] = f2bf(xsr[c]);
#pragma unroll
    for (int c = CC; c < 80; ++c) a16[c] = 0;
#pragma unroll
    for (int k = 0; k < 10; ++k) {
      unsigned int w0 = (unsigned int)a16[8 * k + 0] | ((unsigned int)a16[8 * k + 1] << 16);
      unsigned int w1 = (unsigned int)a16[8 * k + 2] | ((unsigned int)a16[8 * k + 3] << 16);
      unsigned int w2_ = (unsigned int)a16[8 * k + 4] | ((unsigned int)a16[8 * k + 5] << 16);
      unsigned int w3_ = (unsigned int)a16[8 * k + 6] | ((unsigned int)a16[8 * k + 7] << 16);
      *(uint4*)&Acat[(size_t)bn * KP + 8 * k] = make_uint4(w0, w1, w2_, w3_);
    }
  }

  float h1[16];
#pragma unroll
  for (int j = 0; j < 16; ++j) h1[j] = b1[j];
#pragma unroll
  for (int i = 0; i < CC; ++i) {
    float xv = xsr[i];
#pragma unroll
    for (int j = 0; j < 16; ++j) h1[j] = fmaf(xv, w1[i * 16 + j], h1[j]);
  }
#pragma unroll
  for (int j = 0; j < 16; ++j) h1[j] = sigmoidf_(h1[j]);

  float h2[2];
#pragma unroll
  for (int j = 0; j < 2; ++j) {
    float s = b2[j];
#pragma unroll
    for (int i = 0; i < 16; ++i) s = fmaf(h1[i], w2[i * 2 + j], s);
    h2[j] = sigmoidf_(s);
  }

  unsigned short nv16[16];
#pragma unroll
  for (int e = 0; e < EE; ++e) {
    float f = b3[e] + h2[0] * w3[e] + h2[1] * w3[EE + e];
    int be = bn * EE + e;
    float dyn = emb[n * EE + e] * tme[be] * day[be] * spd[be] * occ[be];
    nv16[e] = f2bf(tanhf(dyn * f));
  }
#pragma unroll
  for (int e = EE; e < 16; ++e) nv16[e] = 0;
  unsigned int w[8];
#pragma unroll
  for (int k = 0; k < 8; ++k)
    w[k] = (unsigned int)nv16[2 * k] | ((unsigned int)nv16[2 * k + 1] << 16);
  *(uint4*)&nvP[(size_t)idx * 16]     = make_uint4(w[0], w[1], w[2], w[3]);
  *(uint4*)&nvP[(size_t)idx * 16 + 8] = make_uint4(w[4], w[5], w[6], w[7]);
}

// ---------------- K2: dd[b,n] = rowsum relu(nv nv^T) via MFMA ----------------
__global__ __launch_bounds__(256) void k2_deg(const unsigned short* __restrict__ nvP,
                                              float* __restrict__ dd) {
  int nt = blockIdx.x, b = blockIdx.y;
  int t = threadIdx.x, wid = t >> 6, lane = t & 63;
  int col = lane & 15, q = lane >> 4;
  int n16 = nt * 64 + wid * 16;

  bf16x8 anv = {0, 0, 0, 0, 0, 0, 0, 0};
  if (q < 2) anv = *(const bf16x8*)&nvP[((size_t)(b * NP + n16 + col)) * 16 + q * 8];

  float rs0 = 0.f, rs1 = 0.f, rs2 = 0.f, rs3 = 0.f;
  for (int mb = 0; mb < NP; mb += 16) {
    bf16x8 bfr = {0, 0, 0, 0, 0, 0, 0, 0};
    if (q < 2) bfr = *(const bf16x8*)&nvP[((size_t)(b * NP + mb + col)) * 16 + q * 8];
    f32x4 z = {0.f, 0.f, 0.f, 0.f};
    f32x4 g = __builtin_amdgcn_mfma_f32_16x16x32_bf16(anv, bfr, z, 0, 0, 0);
    rs0 += fmaxf(g[0], 0.f);
    rs1 += fmaxf(g[1], 0.f);
    rs2 += fmaxf(g[2], 0.f);
    rs3 += fmaxf(g[3], 0.f);
  }
#pragma unroll
  for (int off = 1; off < 16; off <<= 1) {
    rs0 += __shfl_xor(rs0, off);
    rs1 += __shfl_xor(rs1, off);
    rs2 += __shfl_xor(rs2, off);
    rs3 += __shfl_xor(rs3, off);
  }
  if (col == 0) {
    int base = b * NP + n16 + q * 4;
    dd[base + 0] = rs0;
    dd[base + 1] = rs1;
    dd[base + 2] = rs2;
    dd[base + 3] = rs3;
  }
}

// ---------------- K2b: d = rsqrt(dd); xsdT[b][c][m] = bf16(d[m]*xs[m][c]) ------------
__global__ __launch_bounds__(256) void k2b_xsd(const float* __restrict__ dd,
                                               const unsigned short* __restrict__ Acat,
                                               float* __restrict__ d_g,
                                               unsigned short* __restrict__ xsdT) {
  int mt = blockIdx.x, b = blockIdx.y, t = threadIdx.x;
  __shared__ float tile[64][67];
  __shared__ float d_s[64];
  int mb = mt * 64;
  if (t < 64) {
    int m = mb + t;
    float dv = 0.f;
    if (m < NN) dv = rsqrtf(dd[b * NP + m]);
    d_s[t] = dv;
    d_g[b * NP + m] = dv;
  }
  for (int idx = t; idx < 64 * CC; idx += 256) {
    int ml = idx / CC, c = idx - ml * CC;
    int m = mb + ml;
    float v = 0.f;
    if (m < NN) v = bf2f(Acat[((size_t)(b * NN + m)) * KP + c]);
    tile[ml][c] = v;
  }
  __syncthreads();
  for (int idx = t; idx < CC * 64; idx += 256) {
    int c = idx >> 6, ml = idx & 63;
    xsdT[((size_t)(b * CC) + c) * NP + mb + ml] = f2bf(tile[ml][c] * d_s[ml]);
  }
}

// ---------------- K3: Acat[bn][80+c] = -d[n] * sum_m relu(nv.nv)[n,m] * xsd[m,c] -----
__global__ __launch_bounds__(256) void k3_agg(const unsigned short* __restrict__ nvP,
                                              const float* __restrict__ d_g,
                                              const unsigned short* __restrict__ xsdT,
                                              unsigned short* __restrict__ Acat) {
  int nt = blockIdx.x, b = blockIdx.y, t = threadIdx.x;
  int wid = t >> 6, lane = t & 63, col = lane & 15, q = lane >> 4;
  int n16 = nt * 64 + wid * 16;
  __shared__ __align__(16) unsigned short As[4][16 * 40];  // per-wave [n16][m32 pad40]
  unsigned short* wAs = As[wid];

  bf16x8 anv = {0, 0, 0, 0, 0, 0, 0, 0};
  if (q < 2) anv = *(const bf16x8*)&nvP[((size_t)(b * NP + n16 + col)) * 16 + q * 8];

  f32x4 acc[5];
#pragma unroll
  for (int ct = 0; ct < 5; ++ct) acc[ct] = (f32x4){0.f, 0.f, 0.f, 0.f};

  for (int mb = 0; mb < NP; mb += 32) {
    bf16x8 b0 = {0, 0, 0, 0, 0, 0, 0, 0};
    bf16x8 b1 = {0, 0, 0, 0, 0, 0, 0, 0};
    if (q < 2) {
      b0 = *(const bf16x8*)&nvP[((size_t)(b * NP + mb + col)) * 16 + q * 8];
      b1 = *(const bf16x8*)&nvP[((size_t)(b * NP + mb + 16 + col)) * 16 + q * 8];
    }
    f32x4 z = {0.f, 0.f, 0.f, 0.f};
    f32x4 g0 = __builtin_amdgcn_mfma_f32_16x16x32_bf16(anv, b0, z, 0, 0, 0);
    f32x4 g1 = __builtin_amdgcn_mfma_f32_16x16x32_bf16(anv, b1, z, 0, 0, 0);
#pragma unroll
    for (int r = 0; r < 4; ++r) {
      wAs[(q * 4 + r) * 40 + col]      = f2bf(fmaxf(g0[r], 0.f));
      wAs[(q * 4 + r) * 40 + col + 16] = f2bf(fmaxf(g1[r], 0.f));
    }
    bf16x8 afr = *(const bf16x8*)&wAs[col * 40 + q * 8];
#pragma unroll
    for (int ct = 0; ct < 5; ++ct) {
      int c = ct * 16 + col;
      bf16x8 xf = {0, 0, 0, 0, 0, 0, 0, 0};
      if (c < CC) xf = *(const bf16x8*)&xsdT[((size_t)(b * CC) + c) * NP + mb + q * 8];
      acc[ct] = __builtin_amdgcn_mfma_f32_16x16x32_bf16(afr, xf, acc[ct], 0, 0, 0);
    }
  }

  float dn[4];
#pragma unroll
  for (int r = 0; r < 4; ++r) dn[r] = d_g[b * NP + n16 + q * 4 + r];
#pragma unroll
  for (int ct = 0; ct < 5; ++ct) {
    int c = ct * 16 + col;   // c in [0,80): zeros beyond 65 land in the pad slots
#pragma unroll
    for (int r = 0; r < 4; ++r) {
      int n = n16 + q * 4 + r;
      if (n < NN)
        Acat[((size_t)(b * NN) + n) * KP + 80 + c] = f2bf(-(acc[ct][r] * dn[r]));
    }
  }
}

// ---------------- K4b: out[b,o] = act( A'[b,:] . W'[o,:] + bias[o] ) via MFMA --------
// grid (NN); 256 thr = 4 waves (wave = 16 b-rows); W' built in LDS per block
template<int OT, bool GATE>
__global__ __launch_bounds__(256) void k4b_gemm(
    const float* __restrict__ emb, const float* __restrict__ wpool,
    const float* __restrict__ bpool, const unsigned short* __restrict__ Acat,
    float* __restrict__ zr_w,
    const float* __restrict__ state, const float* __restrict__ zr_r,
    float* __restrict__ out) {
  int n = blockIdx.x, t = threadIdx.x;
  __shared__ __align__(16) unsigned short Ws[OT * 168];  // [o][k], 84-word rows
  __shared__ float bias_s[OT];

  // ---- W' build: W0+W1 at k=i, W1 at k=80+i ----
  const int OG = OT / 4;            // o-groups of 4 (float4 over o)
  int og = t % OG, ti = t / OG;     // ti strides i
  int o4 = og * 4;
  float em[EE];
#pragma unroll
  for (int e = 0; e < EE; ++e) em[e] = emb[n * EE + e];

  for (int i = ti; i < CC; i += 256 / OG) {
    float4 s0 = make_float4(0.f, 0.f, 0.f, 0.f);
    float4 s1 = make_float4(0.f, 0.f, 0.f, 0.f);
#pragma unroll
    for (int e = 0; e < EE; ++e) {
      float4 w0 = *(const float4*)&wpool[(((size_t)(e * 2 + 0) * CC + i)) * OT + o4];
      float4 w1 = *(const float4*)&wpool[(((size_t)(e * 2 + 1) * CC + i)) * OT + o4];
      s0.x = fmaf(em[e], w0.x, s0.x); s0.y = fmaf(em[e], w0.y, s0.y);
      s0.z = fmaf(em[e], w0.z, s0.z); s0.w = fmaf(em[e], w0.w, s0.w);
      s1.x = fmaf(em[e], w1.x, s1.x); s1.y = fmaf(em[e], w1.y, s1.y);
      s1.z = fmaf(em[e], w1.z, s1.z); s1.w = fmaf(em[e], w1.w, s1.w);
    }
    Ws[(o4 + 0) * 168 + i] = f2bf(s0.x + s1.x);
    Ws[(o4 + 1) * 168 + i] = f2bf(s0.y + s1.y);
    Ws[(o4 + 2) * 168 + i] = f2bf(s0.z + s1.z);
    Ws[(o4 + 3) * 168 + i] = f2bf(s0.w + s1.w);
    Ws[(o4 + 0) * 168 + 80 + i] = f2bf(s1.x);
    Ws[(o4 + 1) * 168 + 80 + i] = f2bf(s1.y);
    Ws[(o4 + 2) * 168 + 80 + i] = f2bf(s1.z);
    Ws[(o4 + 3) * 168 + 80 + i] = f2bf(s1.w);
  }
  // zero pad slots k in [66,80) and [146,160)
  for (int idx = t; idx < OT * 14; idx += 256) {
    int o = idx / 14, kk = idx - o * 14;
    Ws[o * 168 + 66 + kk] = 0;
    Ws[o * 168 + 146 + kk] = 0;
  }
  if (t < OT) {
    float s = 0.f;
#pragma unroll
    for (int e = 0; e < EE; ++e) s = fmaf(em[e] * 0.f + emb[n * EE + e], bpool[e * OT + t], s);
    bias_s[t] = s;
  }
  __syncthreads();

  // ---- GEMM: 4 waves x (16b x OT), K=160 ----
  int wid = t >> 6, lane = t & 63, col = lane & 15, q = lane >> 4;
  int bA = wid * 16 + col;   // A-frag row = batch index
  f32x4 acc[OT / 16];
#pragma unroll
  for (int ot = 0; ot < OT / 16; ++ot) acc[ot] = (f32x4){0.f, 0.f, 0.f, 0.f};

#pragma unroll
  for (int ks = 0; ks < 5; ++ks) {
    bf16x8 af = *(const bf16x8*)&Acat[((size_t)(bA * NN + n)) * KP + ks * 32 + q * 8];
#pragma unroll
    for (int ot = 0; ot < OT / 16; ++ot) {
      bf16x8 bf = *(const bf16x8*)&Ws[(ot * 16 + col) * 168 + ks * 32 + q * 8];
      acc[ot] = __builtin_amdgcn_mfma_f32_16x16x32_bf16(af, bf, acc[ot], 0, 0, 0);
    }
  }

#pragma unroll
  for (int ot = 0; ot < OT / 16; ++ot) {
    int o = ot * 16 + col;
    float bia = bias_s[o];
#pragma unroll
    for (int r = 0; r < 4; ++r) {
      int bb = wid * 16 + q * 4 + r;
      float v = acc[ot][r] + bia;
      if (GATE) {
        zr_w[((size_t)(bb * NN + n)) * 128 + o] = sigmoidf_(v);
      } else {
        float hc = tanhf(v);
        float rr = zr_r[((size_t)(bb * NN + n)) * 128 + 64 + o];
        float st = state[((size_t)(bb * NN + n)) * 64 + o];
        out[((size_t)(bb * NN + n)) * 64 + o] = fmaf(rr, st - hc, hc);
      }
    }
  }
}

extern "C" void kernel_launch(void* const* d_in, const int* in_sizes, int n_in,
                              void* d_out, int out_size, void* d_ws, size_t ws_size,
                              hipStream_t stream) {
  const float* x     = (const float*)d_in[0];
  const float* state = (const float*)d_in[1];
  const float* emb   = (const float*)d_in[2];
  const float* tme   = (const float*)d_in[3];
  const float* day   = (const float*)d_in[4];
  const float* spd   = (const float*)d_in[5];
  const float* occ   = (const float*)d_in[6];
  const float* gwp   = (const float*)d_in[7];
  const float* gbp   = (const float*)d_in[8];
  const float* gw1   = (const float*)d_in[9];
  const float* gb1   = (const float*)d_in[10];
  const float* gw2   = (const float*)d_in[11];
  const float* gb2   = (const float*)d_in[12];
  const float* gw3   = (const float*)d_in[13];
  const float* gb3   = (const float*)d_in[14];
  const float* uwp   = (const float*)d_in[15];
  const float* ubp   = (const float*)d_in[16];
  const float* uw1   = (const float*)d_in[17];
  const float* ub1   = (const float*)d_in[18];
  const float* uw2   = (const float*)d_in[19];
  const float* ub2   = (const float*)d_in[20];
  const float* uw3   = (const float*)d_in[21];
  const float* ub3   = (const float*)d_in[22];

  char* w = (char*)d_ws;
  unsigned short* Acat = (unsigned short*)w;  w += (size_t)BB * NN * KP * 2;  // 18.08 MB
  unsigned short* nvP  = (unsigned short*)w;  w += (size_t)BB * NP * 16 * 2;  // 1.84 MB
  unsigned short* xsdT = (unsigned short*)w;  w += (size_t)BB * CC * NP * 2;  // 7.57 MB
  float* dd   = (float*)w;  w += (size_t)BB * NP * 4;
  float* d_g  = (float*)w;  w += (size_t)BB * NP * 4;
  float* zr   = (float*)w;  w += (size_t)BB * NN * 128 * 4;                   // 28.93 MB

  dim3 b256(256);
  dim3 gK1((BB * NP) / 256);      // 224
  dim3 gK2(14, BB);
  dim3 gK4(NN);

  // phase A (gate)
  k1_hyper<0><<<gK1, b256, 0, stream>>>(x, state, zr, emb, tme, day, spd, occ,
                                        gw1, gb1, gw2, gb2, gw3, gb3, Acat, nvP);
  k2_deg<<<gK2, b256, 0, stream>>>(nvP, dd);
  k2b_xsd<<<gK2, b256, 0, stream>>>(dd, Acat, d_g, xsdT);
  k3_agg<<<gK2, b256, 0, stream>>>(nvP, d_g, xsdT, Acat);
  k4b_gemm<128, true><<<gK4, b256, 0, stream>>>(emb, gwp, gbp, Acat, zr,
                                                nullptr, nullptr, nullptr);
  // phase B (update)
  k1_hyper<1><<<gK1, b256, 0, stream>>>(x, state, zr, emb, tme, day, spd, occ,
                                        uw1, ub1, uw2, ub2, uw3, ub3, Acat, nvP);
  k2_deg<<<gK2, b256, 0, stream>>>(nvP, dd);
  k2b_xsd<<<gK2, b256, 0, stream>>>(dd, Acat, d_g, xsdT);
  k3_agg<<<gK2, b256, 0, stream>>>(nvP, d_g, xsdT, Acat);
  k4b_gemm<64, false><<<gK4, b256, 0, stream>>>(emb, uwp, ubp, Acat, nullptr,
                                                state, zr, (float*)d_out);
}